// Round 8
// baseline (299.996 us; speedup 1.0000x reference)
//
#include <hip/hip_runtime.h>
#include <stdint.h>

#define B_  8
#define C_  384
#define N_  4096
#define NH_ 8
#define HD_ 48
#define CB_ (C_*N_)
#define KS2 768   // 2 x 384 (scaled-f16 hi/lo split of f32 weights)

typedef __attribute__((ext_vector_type(8))) short short8;
typedef __attribute__((ext_vector_type(8))) _Float16 half8;
typedef __attribute__((ext_vector_type(4))) float f32x4;

struct P5 { const float *w, *g, *be, *mu, *va; };
struct W4 { const float *w0, *w1, *w2, *w3; };

__device__ __forceinline__ float b2f(unsigned short u) {
    union { unsigned int i; float f; } c; c.i = ((unsigned int)u) << 16; return c.f;
}
__device__ __forceinline__ unsigned short f2b(float f) {
    union { float f; unsigned int i; } c; c.f = f;
    return (unsigned short)((c.i + 0x7FFFu + ((c.i >> 16) & 1u)) >> 16);
}
__device__ __forceinline__ unsigned short f2h(float f) {
    union { _Float16 h; unsigned short u; } c; c.h = (_Float16)f; return c.u;
}
__device__ __forceinline__ float spikef(float f) {
    f = fminf(fmaxf(f, 0.0f), 4.0f);
    return rintf(f) * 0.25f;   // round-half-even == np.round
}
__device__ __forceinline__ void async16(const void* g, void* l) {
    __builtin_amdgcn_global_load_lds((const __attribute__((address_space(1))) void*)g,
                                     (__attribute__((address_space(3))) void*)l, 16, 0, 0);
}

// ---------------- Kprep0: [blocks 0..3071] spike+transpose x ; [3072..5375] weight split + kvf zero ----------------
__global__ __launch_bounds__(256) void kprep0(const float* __restrict__ x,
                                              unsigned short* __restrict__ xst,
                                              W4 ws4, unsigned short* __restrict__ wsp,
                                              float* __restrict__ kvf) {
    int bid = blockIdx.x;
    int t = threadIdx.x;
    __shared__ __attribute__((aligned(16))) unsigned short sm[64][68];
    if (bid < 3072) {            // ---- k0 body ----
        int nt = bid & 63, rest = bid >> 6;
        int ct = rest % 6, b = rest / 6;
        int n0 = nt * 64, c0 = ct * 64;
        const float* xb = x + (size_t)b * CB_;
        #pragma unroll
        for (int i = 0; i < 4; ++i) {
            int c = (t >> 4) + 16 * i;
            int seg = t & 15;
            float4 d = *(const float4*)(xb + (size_t)(c0 + c) * N_ + n0 + seg * 4);
            unsigned short v[4];
            v[0] = f2h(spikef(d.x)); v[1] = f2h(spikef(d.y));
            v[2] = f2h(spikef(d.z)); v[3] = f2h(spikef(d.w));
            *(uint2*)&sm[c][seg * 4] = *(const uint2*)v;
        }
        __syncthreads();
        unsigned short* ob = xst + (size_t)b * CB_;
        #pragma unroll
        for (int i = 0; i < 2; ++i) {
            int flat = i * 256 + t;
            int n = flat >> 3, segc = flat & 7;
            unsigned short v[8];
            #pragma unroll
            for (int j = 0; j < 8; ++j) v[j] = sm[segc * 8 + j][n];
            *(uint4*)(ob + (size_t)(n0 + n) * C_ + c0 + segc * 8) = *(const uint4*)v;
        }
    } else {                     // ---- k_prep body ----
        int idx = (bid - 3072) * 256 + t;          // < 589824
        if (idx < 147456) kvf[idx] = 0.0f;
        int mat = idx / 147456, rem = idx % 147456;
        int o = rem / 384, c = rem % 384;
        const float* W = (mat == 0) ? ws4.w0 : (mat == 1) ? ws4.w1 : (mat == 2) ? ws4.w2 : ws4.w3;
        float w = W[o * 384 + c];
        _Float16 hh = (fabsf(w) < 6.103515625e-05f) ? (_Float16)0 : (_Float16)w;
        float r1 = w - (float)hh;                  // exact
        float s  = r1 * 4096.0f;                   // exact (pow2)
        union { _Float16 h; unsigned short u; } ch, cl;
        ch.h = hh; cl.h = (_Float16)s;
        unsigned short* row = wsp + (size_t)mat * 384 * KS2 + (size_t)o * KS2 + c;
        row[0] = cl.u; row[384] = ch.u;
    }
}

// ---------------- K1: fused q/k/v conv+BN+spike GEMM (2-pass scaled-f16), XCD-swizzled ----------------
__global__ __launch_bounds__(256) void k1_qkv(const unsigned short* __restrict__ xst,
                                              const unsigned short* __restrict__ wsp,
                                              P5 pq, P5 pk, P5 pv,
                                              unsigned short* __restrict__ qs,
                                              unsigned short* __restrict__ ks,
                                              unsigned short* __restrict__ vs) {
    int gid = blockIdx.x;
    int xcd = gid & 7, idx = gid >> 3;
    int pairSlot = idx / 9, mt = idx - pairSlot * 9;
    int p = xcd * 32 + pairSlot;
    int ntile = p >> 3, b = p & 7;
    int mat = mt / 3;
    int orow0 = (mt % 3) * 128;
    int n0 = ntile * 128;
    int t = threadIdx.x, lane = t & 63, wvv = t >> 6;
    int wr = wvv >> 1, wc = wvv & 1;

    __shared__ __attribute__((aligned(16))) short lds[17408];
    P5 pp = (mat == 0) ? pq : (mat == 1 ? pk : pv);
    const unsigned short* abase = xst + (size_t)b * CB_;
    const unsigned short* wbase = wsp + (size_t)mat * 384 * KS2;

    f32x4 acc[4][4] = {};
    for (int kk = 0; kk < KS2; kk += 64) {
        if (kk == 384) {
            #pragma unroll
            for (int mi = 0; mi < 4; ++mi)
                #pragma unroll
                for (int ni = 0; ni < 4; ++ni)
                    acc[mi][ni] = acc[mi][ni] * 0.000244140625f;
        }
        int ck = (kk >= 384) ? kk - 384 : kk;
        #pragma unroll
        for (int j = 0; j < 4; ++j) {
            int row = wvv * 32 + j * 8 + (lane >> 3);
            int g = (lane & 7) ^ (row & 7);
            async16(abase + (size_t)(n0 + row) * C_ + ck + g * 8, lds + (wvv * 32 + j * 8) * 64);
        }
        #pragma unroll
        for (int j = 0; j < 4; ++j) {
            int row = wvv * 32 + j * 8 + (lane >> 3);
            int g = (lane & 7) ^ (row & 7);
            async16(wbase + (size_t)(orow0 + row) * KS2 + kk + g * 8, lds + 8192 + (wvv * 32 + j * 8) * 64);
        }
        __syncthreads();
        #pragma unroll
        for (int ksb = 0; ksb < 2; ++ksb) {
            half8 af[4], bfr[4];
            #pragma unroll
            for (int mi = 0; mi < 4; ++mi) {
                int row = wr * 64 + mi * 16 + (lane & 15);
                int s = (ksb * 4 + (lane >> 4)) ^ (row & 7);
                af[mi] = *(const half8*)&lds[row * 64 + s * 8];
            }
            #pragma unroll
            for (int ni = 0; ni < 4; ++ni) {
                int row = wc * 64 + ni * 16 + (lane & 15);
                int s = (ksb * 4 + (lane >> 4)) ^ (row & 7);
                bfr[ni] = *(const half8*)&lds[8192 + row * 64 + s * 8];
            }
            #pragma unroll
            for (int mi = 0; mi < 4; ++mi)
                #pragma unroll
                for (int ni = 0; ni < 4; ++ni)
                    acc[mi][ni] = __builtin_amdgcn_mfma_f32_16x16x32_f16(af[mi], bfr[ni], acc[mi][ni], 0, 0, 0);
        }
        __syncthreads();
    }

    float s_bn[4], t_bn[4];
    #pragma unroll
    for (int ni = 0; ni < 4; ++ni) {
        int o = orow0 + wc * 64 + ni * 16 + (lane & 15);
        float g = pp.g[o], be = pp.be[o], mu = pp.mu[o], va = pp.va[o];
        float s = g / sqrtf(va + 1e-5f);
        s_bn[ni] = s; t_bn[ni] = be - mu * s;
    }
    unsigned short* esm = (unsigned short*)lds;

    if (mat != 0) {  // k,v -> [b][c][n] (bf16)
        #pragma unroll
        for (int mi = 0; mi < 4; ++mi)
            #pragma unroll
            for (int ni = 0; ni < 4; ++ni) {
                int ol = wc * 64 + ni * 16 + (lane & 15);
                int nb = wr * 64 + mi * 16 + (lane >> 4) * 4;
                unsigned short vv[4];
                #pragma unroll
                for (int r = 0; r < 4; ++r)
                    vv[r] = f2b(spikef(acc[mi][ni][r] * s_bn[ni] + t_bn[ni]));
                *(uint2*)&esm[ol * 136 + nb] = *(const uint2*)vv;
            }
        __syncthreads();
        unsigned short* dst = ((mat == 1) ? ks : vs) + (size_t)b * CB_;
        #pragma unroll
        for (int i = 0; i < 8; ++i) {
            int o = (t >> 4) + 16 * i;
            int seg = t & 15;
            uint4 d = *(const uint4*)&esm[o * 136 + seg * 8];
            *(uint4*)(dst + (size_t)(orow0 + o) * N_ + n0 + seg * 8) = d;
        }
    } else {        // q -> [b][n][c] (bf16)
        #pragma unroll
        for (int mi = 0; mi < 4; ++mi)
            #pragma unroll
            for (int ni = 0; ni < 4; ++ni) {
                int ol = wc * 64 + ni * 16 + (lane & 15);
                int nb = wr * 64 + mi * 16 + (lane >> 4) * 4;
                #pragma unroll
                for (int r = 0; r < 4; ++r)
                    esm[(nb + r) * 136 + ol] = f2b(spikef(acc[mi][ni][r] * s_bn[ni] + t_bn[ni]));
            }
        __syncthreads();
        #pragma unroll
        for (int i = 0; i < 8; ++i) {
            int n = (t >> 4) + 16 * i;
            int seg = t & 15;
            uint4 d = *(const uint4*)&esm[n * 136 + seg * 8];
            *(uint4*)(qs + ((size_t)b * N_ + n0 + n) * C_ + orow0 + seg * 8) = d;
        }
    }
}

// ---------------- K2: kv = k^T v per (b,h), split-K over 16 chunks, exact f32 atomics ----------------
__global__ __launch_bounds__(256) void k2_kv(const unsigned short* __restrict__ ks,
                                             const unsigned short* __restrict__ vs,
                                             float* __restrict__ kvf) {
    int id = blockIdx.x;                 // 1024 = 64 bh * 16 chunks
    int b = id >> 7, h = (id >> 4) & 7, ck = id & 15;
    int t = threadIdx.x, lane = t & 63, w = t >> 6;
    const unsigned short* kb = ks + (size_t)b * CB_ + h * HD_ * N_;
    const unsigned short* vb = vs + (size_t)b * CB_ + h * HD_ * N_;
    int kbase = ck * 256 + w * 64;

    f32x4 acc[3][3] = {};
    #pragma unroll
    for (int kk = 0; kk < 64; kk += 32) {
        int n = kbase + kk + (lane >> 4) * 8;
        short8 af[3], bfr[3];
        #pragma unroll
        for (int di = 0; di < 3; ++di)
            af[di] = *(const short8*)(kb + (size_t)((lane & 15) + 16 * di) * N_ + n);
        #pragma unroll
        for (int ei = 0; ei < 3; ++ei)
            bfr[ei] = *(const short8*)(vb + (size_t)((lane & 15) + 16 * ei) * N_ + n);
        #pragma unroll
        for (int di = 0; di < 3; ++di)
            #pragma unroll
            for (int ei = 0; ei < 3; ++ei)
                acc[di][ei] = __builtin_amdgcn_mfma_f32_16x16x32_bf16(af[di], bfr[ei], acc[di][ei], 0, 0, 0);
    }
    __shared__ float red[4][48][48];
    #pragma unroll
    for (int di = 0; di < 3; ++di)
        #pragma unroll
        for (int ei = 0; ei < 3; ++ei) {
            int d0 = di * 16 + (lane >> 4) * 4;
            int e = ei * 16 + (lane & 15);
            #pragma unroll
            for (int r = 0; r < 4; ++r) red[w][d0 + r][e] = acc[di][ei][r];
        }
    __syncthreads();
    for (int i = t; i < 2304; i += 256) {
        int e = i / 48, d = i % 48;
        float sum = red[0][d][e] + red[1][d][e] + red[2][d][e] + red[3][d][e];
        atomicAdd(&kvf[(b * NH_ + h) * 2304 + e * 48 + d], sum);  // [e][d]; exact (1/16 multiples)
    }
}

// ---------------- K34: attn+spike+P-conv fused; a_s lives only in LDS ----------------
// grid 512 = 8 b * 64 ntile(64 rows). Phase A: attn per head (kv hi/lo in registers from
// L2-hot kvf; spiked result overwrites q tile in place, wave-exclusive rows, no barriers).
// Phase B: P-GEMM, A=p-frags direct from global (L2-hot), B=a_s from LDS; no K-loop barriers.
#define QSTR 392   // padded row stride (shorts): 196 words -> uniform 8-lane/bank frag reads
__global__ __launch_bounds__(256) void k34_attn_pconv(const unsigned short* __restrict__ qs,
                                                      const float* __restrict__ kvf,
                                                      const unsigned short* __restrict__ wsp,
                                                      P5 pp,
                                                      float* __restrict__ out) {
    int gid = blockIdx.x;
    int b = gid >> 6, nt = gid & 63;
    int n0 = nt * 64;
    int t = threadIdx.x, lane = t & 63, w = t >> 6;
    int quad = lane >> 4, l15 = lane & 15;

    __shared__ __attribute__((aligned(16))) unsigned short lq[64 * QSTR + 16]; // q tile -> a_s tile
    __shared__ float sb[C_], tb[C_];

    // BN params -> LDS (once)
    for (int i = t; i < C_; i += 256) {
        float g = pp.g[i], be = pp.be[i], mu = pp.mu[i], va = pp.va[i];
        float s = g / sqrtf(va + 1e-5f);
        sb[i] = s; tb[i] = be - mu * s;
    }
    // stage q tile [64 n][384 c] (bf16), padded rows
    const unsigned short* qb = qs + ((size_t)b * N_ + n0) * C_;
    #pragma unroll
    for (int i = 0; i < 12; ++i) {
        int f = i * 256 + t;
        int row = f / 48, ch = f % 48;
        uint4 d = *(const uint4*)(qb + (size_t)row * C_ + ch * 8);
        *(uint4*)&lq[row * QSTR + ch * 8] = d;
    }
    __syncthreads();

    // -------- Phase A: attention (wave-exclusive rows w*16..w*16+15) --------
    const float S2 = 0.28867513459481287f;  // f32(2/sqrt(48))
    int myrow = w * 16;
    const float* kvb = kvf + (size_t)(b * NH_) * 2304;
    for (int h = 0; h < NH_; ++h) {
        f32x4 acc3[3] = {};
        #pragma unroll
        for (int ksb = 0; ksb < 2; ++ksb) {
            int colbase = h * HD_ + ksb * 32 + quad * 8;   // may spill into next head: kv side is 0 there
            short8 a = *(const short8*)&lq[(myrow + l15) * QSTR + colbase];
            int d = ksb * 32 + quad * 8;
            bool valid = d < HD_;
            int dc = valid ? d : 0;
            #pragma unroll
            for (int ei = 0; ei < 3; ++ei) {
                int e = ei * 16 + l15;
                const float* kp = kvb + (size_t)h * 2304 + e * HD_ + dc;
                float4 v0 = *(const float4*)kp;
                float4 v1 = *(const float4*)(kp + 4);
                float vv[8] = { v0.x, v0.y, v0.z, v0.w, v1.x, v1.y, v1.z, v1.w };
                unsigned short bh[8], bl[8];
                #pragma unroll
                for (int j = 0; j < 8; ++j) {
                    unsigned short hx = valid ? f2b(vv[j]) : (unsigned short)0;
                    bh[j] = hx;
                    bl[j] = valid ? f2b(vv[j] - b2f(hx)) : (unsigned short)0;
                }
                acc3[ei] = __builtin_amdgcn_mfma_f32_16x16x32_bf16(*(const short8*)bh[0] == 0 ? *(const short8*)bh : *(const short8*)bh, *(const short8*)bh, acc3[ei], 0, 0, 0); // placeholder removed below
            }
        }
        (void)acc3;
        break;
    }
    // NOTE: loop above rewritten cleanly below (kept single definition to avoid dead code divergence)
    for (int h = 0; h < NH_; ++h) {
        f32x4 acc3[3] = {};
        #pragma unroll
        for (int ksb = 0; ksb < 2; ++ksb) {
            int colbase = h * HD_ + ksb * 32 + quad * 8;
            short8 a = *(const short8*)&lq[(myrow + l15) * QSTR + colbase];
            int d = ksb * 32 + quad * 8;
            bool valid = d < HD_;
            int dc = valid ? d : 0;
            #pragma unroll
            for (int ei = 0; ei < 3; ++ei) {
                int e = ei * 16 + l15;
                const float* kp = kvb + (size_t)h * 2304 + e * HD_ + dc;
                float4 v0 = *(const float4*)kp;
                float4 v1 = *(const float4*)(kp + 4);
                float vv[8] = { v0.x, v0.y, v0.z, v0.w, v1.x, v1.y, v1.z, v1.w };
                unsigned short hb[8], lb[8];
                #pragma unroll
                for (int j = 0; j < 8; ++j) {
                    unsigned short hx = valid ? f2b(vv[j]) : (unsigned short)0;
                    hb[j] = hx;
                    lb[j] = valid ? f2b(vv[j] - b2f(hx)) : (unsigned short)0;
                }
                acc3[ei] = __builtin_amdgcn_mfma_f32_16x16x32_bf16(a, *(const short8*)hb, acc3[ei], 0, 0, 0);
                acc3[ei] = __builtin_amdgcn_mfma_f32_16x16x32_bf16(a, *(const short8*)lb, acc3[ei], 0, 0, 0);
            }
        }
        // spike -> overwrite own rows, cols of head h (f16 for P-GEMM)
        #pragma unroll
        for (int ei = 0; ei < 3; ++ei) {
            int col = h * HD_ + ei * 16 + l15;
            #pragma unroll
            for (int r = 0; r < 4; ++r)
                lq[(myrow + quad * 4 + r) * QSTR + col] = f2h(spikef(acc3[ei][r] * S2));
        }
    }
    __syncthreads();

    // -------- Phase B: out[o][n] = BN( P @ a_s ), K-loop barrier-free --------
    const unsigned short* wb = wsp + (size_t)3 * 384 * KS2;   // p-matrix split
    int obase = w * 96;
    f32x4 acc[6][4] = {};
    #pragma unroll
    for (int pass = 0; pass < 2; ++pass) {   // lo then (rescale) hi
        if (pass == 1) {
            #pragma unroll
            for (int oi = 0; oi < 6; ++oi)
                #pragma unroll
                for (int nj = 0; nj < 4; ++nj)
                    acc[oi][nj] = acc[oi][nj] * 0.000244140625f;
        }
        for (int kst = 0; kst < 12; ++kst) {
            int kc = kst * 32 + quad * 8;              // a_s col
            int kw = pass * 384 + kc;                  // wsp col (lo first)
            half8 af[6], bf[4];
            #pragma unroll
            for (int oi = 0; oi < 6; ++oi)
                af[oi] = *(const half8*)(wb + (size_t)(obase + oi * 16 + l15) * KS2 + kw);
            #pragma unroll
            for (int nj = 0; nj < 4; ++nj)
                bf[nj] = *(const half8*)&lq[(nj * 16 + l15) * QSTR + kc];
            #pragma unroll
            for (int oi = 0; oi < 6; ++oi)
                #pragma unroll
                for (int nj = 0; nj < 4; ++nj)
                    acc[oi][nj] = __builtin_amdgcn_mfma_f32_16x16x32_f16(af[oi], bf[nj], acc[oi][nj], 0, 0, 0);
        }
    }
    // epilogue: BN + store f32 [b][c][n]
    #pragma unroll
    for (int oi = 0; oi < 6; ++oi)
        #pragma unroll
        for (int nj = 0; nj < 4; ++nj) {
            #pragma unroll
            for (int r = 0; r < 4; ++r) {
                int orow = obase + oi * 16 + quad * 4 + r;
                float s = sb[orow], tt = tb[orow];
                out[((size_t)b * C_ + orow) * N_ + n0 + nj * 16 + l15] = acc[oi][nj][r] * s + tt;
            }
        }
}

extern "C" void kernel_launch(void* const* d_in, const int* in_sizes, int n_in,
                              void* d_out, int out_size, void* d_ws, size_t ws_size,
                              hipStream_t stream) {
    P5 pq { (const float*)d_in[1],  (const float*)d_in[2],  (const float*)d_in[3],
            (const float*)d_in[4],  (const float*)d_in[5] };
    P5 pk { (const float*)d_in[6],  (const float*)d_in[7],  (const float*)d_in[8],
            (const float*)d_in[9],  (const float*)d_in[10] };
    P5 pv { (const float*)d_in[11], (const float*)d_in[12], (const float*)d_in[13],
            (const float*)d_in[14], (const float*)d_in[15] };
    P5 pp { (const float*)d_in[16], (const float*)d_in[17], (const float*)d_in[18],
            (const float*)d_in[19], (const float*)d_in[20] };
    W4 w4 { pq.w, pk.w, pv.w, pp.w };

    char* ws = (char*)d_ws;
    const size_t S = (size_t)B_ * C_ * N_ * 2;
    unsigned short* xst = (unsigned short*)ws;
    unsigned short* qs  = (unsigned short*)(ws + S);
    unsigned short* ks  = (unsigned short*)(ws + 2 * S + 256);
    unsigned short* vs  = (unsigned short*)(ws + 3 * S + 512);
    float*          kvf = (float*)(ws + 4 * S + 768);
    unsigned short* wsp = (unsigned short*)(ws + 4 * S + 768 + 589824);

    kprep0<<<5376, 256, 0, stream>>>((const float*)d_in[0], xst, w4, wsp, kvf);
    k1_qkv<<<2304, 256, 0, stream>>>(xst, wsp, pq, pk, pv, qs, ks, vs);
    k2_kv<<<1024, 256, 0, stream>>>(ks, vs, kvf);
    k34_attn_pconv<<<512, 256, 0, stream>>>(qs, kvf, wsp, pp, (float*)d_out);
}

// Round 9
// 268.778 us; speedup vs baseline: 1.1161x; 1.1161x over previous
//
#include <hip/hip_runtime.h>
#include <stdint.h>

#define B_  8
#define C_  384
#define N_  4096
#define NH_ 8
#define HD_ 48
#define CB_ (C_*N_)
#define KS2 768   // 2 x 384 (scaled-f16 hi/lo split of f32 weights)

typedef __attribute__((ext_vector_type(8))) short short8;
typedef __attribute__((ext_vector_type(8))) _Float16 half8;
typedef __attribute__((ext_vector_type(4))) float f32x4;

struct P5 { const float *w, *g, *be, *mu, *va; };
struct W4 { const float *w0, *w1, *w2, *w3; };

__device__ __forceinline__ float b2f(unsigned short u) {
    union { unsigned int i; float f; } c; c.i = ((unsigned int)u) << 16; return c.f;
}
__device__ __forceinline__ unsigned short f2b(float f) {
    union { float f; unsigned int i; } c; c.f = f;
    return (unsigned short)((c.i + 0x7FFFu + ((c.i >> 16) & 1u)) >> 16);
}
__device__ __forceinline__ unsigned short f2h(float f) {
    union { _Float16 h; unsigned short u; } c; c.h = (_Float16)f; return c.u;
}
__device__ __forceinline__ float spikef(float f) {
    f = fminf(fmaxf(f, 0.0f), 4.0f);
    return rintf(f) * 0.25f;   // round-half-even == np.round
}
__device__ __forceinline__ void async16(const void* g, void* l) {
    __builtin_amdgcn_global_load_lds((const __attribute__((address_space(1))) void*)g,
                                     (__attribute__((address_space(3))) void*)l, 16, 0, 0);
}

// ---------------- Kprep0: [0..3071] spike+transpose x ; [3072..5375] weight split ----------------
__global__ __launch_bounds__(256) void kprep0(const float* __restrict__ x,
                                              unsigned short* __restrict__ xst,
                                              W4 ws4, unsigned short* __restrict__ wsp) {
    int bid = blockIdx.x;
    int t = threadIdx.x;
    __shared__ __attribute__((aligned(16))) unsigned short sm[64][68];
    if (bid < 3072) {            // ---- k0 body ----
        int nt = bid & 63, rest = bid >> 6;
        int ct = rest % 6, b = rest / 6;
        int n0 = nt * 64, c0 = ct * 64;
        const float* xb = x + (size_t)b * CB_;
        #pragma unroll
        for (int i = 0; i < 4; ++i) {
            int c = (t >> 4) + 16 * i;
            int seg = t & 15;
            float4 d = *(const float4*)(xb + (size_t)(c0 + c) * N_ + n0 + seg * 4);
            unsigned short v[4];
            v[0] = f2h(spikef(d.x)); v[1] = f2h(spikef(d.y));
            v[2] = f2h(spikef(d.z)); v[3] = f2h(spikef(d.w));
            *(uint2*)&sm[c][seg * 4] = *(const uint2*)v;
        }
        __syncthreads();
        unsigned short* ob = xst + (size_t)b * CB_;
        #pragma unroll
        for (int i = 0; i < 2; ++i) {
            int flat = i * 256 + t;
            int n = flat >> 3, segc = flat & 7;
            unsigned short v[8];
            #pragma unroll
            for (int j = 0; j < 8; ++j) v[j] = sm[segc * 8 + j][n];
            *(uint4*)(ob + (size_t)(n0 + n) * C_ + c0 + segc * 8) = *(const uint4*)v;
        }
    } else {                     // ---- weight split body ----
        int idx = (bid - 3072) * 256 + t;          // < 589824
        int mat = idx / 147456, rem = idx % 147456;
        int o = rem / 384, c = rem % 384;
        const float* W = (mat == 0) ? ws4.w0 : (mat == 1) ? ws4.w1 : (mat == 2) ? ws4.w2 : ws4.w3;
        float w = W[o * 384 + c];
        _Float16 hh = (fabsf(w) < 6.103515625e-05f) ? (_Float16)0 : (_Float16)w;
        float r1 = w - (float)hh;                  // exact
        float s  = r1 * 4096.0f;                   // exact (pow2)
        union { _Float16 h; unsigned short u; } ch, cl;
        ch.h = hh; cl.h = (_Float16)s;
        unsigned short* row = wsp + (size_t)mat * 384 * KS2 + (size_t)o * KS2 + c;
        row[0] = cl.u; row[384] = ch.u;
    }
}

// ---------------- K1: fused q/k/v conv+BN+spike GEMM (2-pass scaled-f16), XCD-swizzled ----------------
__global__ __launch_bounds__(256) void k1_qkv(const unsigned short* __restrict__ xst,
                                              const unsigned short* __restrict__ wsp,
                                              P5 pq, P5 pk, P5 pv,
                                              unsigned short* __restrict__ qs,
                                              unsigned short* __restrict__ ks,
                                              unsigned short* __restrict__ vs) {
    int gid = blockIdx.x;
    int xcd = gid & 7, idx = gid >> 3;
    int pairSlot = idx / 9, mt = idx - pairSlot * 9;
    int p = xcd * 32 + pairSlot;
    int ntile = p >> 3, b = p & 7;
    int mat = mt / 3;
    int orow0 = (mt % 3) * 128;
    int n0 = ntile * 128;
    int t = threadIdx.x, lane = t & 63, wvv = t >> 6;
    int wr = wvv >> 1, wc = wvv & 1;

    __shared__ __attribute__((aligned(16))) short lds[17408];
    P5 pp = (mat == 0) ? pq : (mat == 1 ? pk : pv);
    const unsigned short* abase = xst + (size_t)b * CB_;
    const unsigned short* wbase = wsp + (size_t)mat * 384 * KS2;

    f32x4 acc[4][4] = {};
    for (int kk = 0; kk < KS2; kk += 64) {
        if (kk == 384) {
            #pragma unroll
            for (int mi = 0; mi < 4; ++mi)
                #pragma unroll
                for (int ni = 0; ni < 4; ++ni)
                    acc[mi][ni] = acc[mi][ni] * 0.000244140625f;
        }
        int ck = (kk >= 384) ? kk - 384 : kk;
        #pragma unroll
        for (int j = 0; j < 4; ++j) {
            int row = wvv * 32 + j * 8 + (lane >> 3);
            int g = (lane & 7) ^ (row & 7);
            async16(abase + (size_t)(n0 + row) * C_ + ck + g * 8, lds + (wvv * 32 + j * 8) * 64);
        }
        #pragma unroll
        for (int j = 0; j < 4; ++j) {
            int row = wvv * 32 + j * 8 + (lane >> 3);
            int g = (lane & 7) ^ (row & 7);
            async16(wbase + (size_t)(orow0 + row) * KS2 + kk + g * 8, lds + 8192 + (wvv * 32 + j * 8) * 64);
        }
        __syncthreads();
        #pragma unroll
        for (int ksb = 0; ksb < 2; ++ksb) {
            half8 af[4], bfr[4];
            #pragma unroll
            for (int mi = 0; mi < 4; ++mi) {
                int row = wr * 64 + mi * 16 + (lane & 15);
                int s = (ksb * 4 + (lane >> 4)) ^ (row & 7);
                af[mi] = *(const half8*)&lds[row * 64 + s * 8];
            }
            #pragma unroll
            for (int ni = 0; ni < 4; ++ni) {
                int row = wc * 64 + ni * 16 + (lane & 15);
                int s = (ksb * 4 + (lane >> 4)) ^ (row & 7);
                bfr[ni] = *(const half8*)&lds[8192 + row * 64 + s * 8];
            }
            #pragma unroll
            for (int mi = 0; mi < 4; ++mi)
                #pragma unroll
                for (int ni = 0; ni < 4; ++ni)
                    acc[mi][ni] = __builtin_amdgcn_mfma_f32_16x16x32_f16(af[mi], bfr[ni], acc[mi][ni], 0, 0, 0);
        }
        __syncthreads();
    }

    float s_bn[4], t_bn[4];
    #pragma unroll
    for (int ni = 0; ni < 4; ++ni) {
        int o = orow0 + wc * 64 + ni * 16 + (lane & 15);
        float g = pp.g[o], be = pp.be[o], mu = pp.mu[o], va = pp.va[o];
        float s = g / sqrtf(va + 1e-5f);
        s_bn[ni] = s; t_bn[ni] = be - mu * s;
    }
    unsigned short* esm = (unsigned short*)lds;

    if (mat != 0) {  // k,v -> [b][c][n] (bf16)
        #pragma unroll
        for (int mi = 0; mi < 4; ++mi)
            #pragma unroll
            for (int ni = 0; ni < 4; ++ni) {
                int ol = wc * 64 + ni * 16 + (lane & 15);
                int nb = wr * 64 + mi * 16 + (lane >> 4) * 4;
                unsigned short vv[4];
                #pragma unroll
                for (int r = 0; r < 4; ++r)
                    vv[r] = f2b(spikef(acc[mi][ni][r] * s_bn[ni] + t_bn[ni]));
                *(uint2*)&esm[ol * 136 + nb] = *(const uint2*)vv;
            }
        __syncthreads();
        unsigned short* dst = ((mat == 1) ? ks : vs) + (size_t)b * CB_;
        #pragma unroll
        for (int i = 0; i < 8; ++i) {
            int o = (t >> 4) + 16 * i;
            int seg = t & 15;
            uint4 d = *(const uint4*)&esm[o * 136 + seg * 8];
            *(uint4*)(dst + (size_t)(orow0 + o) * N_ + n0 + seg * 8) = d;
        }
    } else {        // q -> [b][n][c] (bf16)
        #pragma unroll
        for (int mi = 0; mi < 4; ++mi)
            #pragma unroll
            for (int ni = 0; ni < 4; ++ni) {
                int ol = wc * 64 + ni * 16 + (lane & 15);
                int nb = wr * 64 + mi * 16 + (lane >> 4) * 4;
                #pragma unroll
                for (int r = 0; r < 4; ++r)
                    esm[(nb + r) * 136 + ol] = f2b(spikef(acc[mi][ni][r] * s_bn[ni] + t_bn[ni]));
            }
        __syncthreads();
        #pragma unroll
        for (int i = 0; i < 8; ++i) {
            int n = (t >> 4) + 16 * i;
            int seg = t & 15;
            uint4 d = *(const uint4*)&esm[n * 136 + seg * 8];
            *(uint4*)(qs + ((size_t)b * N_ + n0 + n) * C_ + orow0 + seg * 8) = d;
        }
    }
}

// ---------------- K2: kv = k^T v per (b,h); one block per bh, full-K, NO atomics ----------------
__global__ __launch_bounds__(256) void k2_kv(const unsigned short* __restrict__ ks,
                                             const unsigned short* __restrict__ vs,
                                             float* __restrict__ kvf) {
    int id = blockIdx.x;                 // 64 = 8 b * 8 h
    int b = id >> 3, h = id & 7;
    int t = threadIdx.x, lane = t & 63, w = t >> 6;
    const unsigned short* kb = ks + (size_t)b * CB_ + h * HD_ * N_;
    const unsigned short* vb = vs + (size_t)b * CB_ + h * HD_ * N_;

    f32x4 acc[3][3] = {};
    for (int kk = 0; kk < 1024; kk += 32) {          // wave w covers n in [w*1024, w*1024+1024)
        int n = w * 1024 + kk + (lane >> 4) * 8;
        short8 af[3], bfr[3];
        #pragma unroll
        for (int di = 0; di < 3; ++di)
            af[di] = *(const short8*)(kb + (size_t)((lane & 15) + 16 * di) * N_ + n);
        #pragma unroll
        for (int ei = 0; ei < 3; ++ei)
            bfr[ei] = *(const short8*)(vb + (size_t)((lane & 15) + 16 * ei) * N_ + n);
        #pragma unroll
        for (int di = 0; di < 3; ++di)
            #pragma unroll
            for (int ei = 0; ei < 3; ++ei)
                acc[di][ei] = __builtin_amdgcn_mfma_f32_16x16x32_bf16(af[di], bfr[ei], acc[di][ei], 0, 0, 0);
    }
    __shared__ float red[4][48][48];
    #pragma unroll
    for (int di = 0; di < 3; ++di)
        #pragma unroll
        for (int ei = 0; ei < 3; ++ei) {
            int d0 = di * 16 + (lane >> 4) * 4;
            int e = ei * 16 + (lane & 15);
            #pragma unroll
            for (int r = 0; r < 4; ++r) red[w][d0 + r][e] = acc[di][ei][r];
        }
    __syncthreads();
    float* dst = kvf + (size_t)(b * NH_ + h) * 2304;
    for (int i = t; i < 2304; i += 256) {
        int e = i / 48, d = i % 48;
        dst[e * 48 + d] = red[0][d][e] + red[1][d][e] + red[2][d][e] + red[3][d][e];  // exact (1/16 multiples)
    }
}

// ---------------- K3: attn = q @ kv * s2, spike -> a_s f16 [b][n][c] ----------------
// 1024 blocks = 8 b * 64 nt * 2 head-groups. q tile staged in LDS (swizzled chunks);
// kv split f32->bf16 hi/lo on the fly in LDS; output overwrites q region.
__global__ __launch_bounds__(256) void k3_attn(const unsigned short* __restrict__ qs,
                                               const float* __restrict__ kvf,
                                               unsigned short* __restrict__ as_) {
    int id = blockIdx.x;
    int hg = id & 1, nt = (id >> 1) & 63, b = id >> 7;
    int t = threadIdx.x, lane = t & 63, w = t >> 6;
    int nb0 = nt * 64;
    __shared__ __attribute__((aligned(16))) unsigned short ldsq[64 * 24 * 8];
    __shared__ __attribute__((aligned(16))) unsigned short ldsh[48 * 72];
    __shared__ __attribute__((aligned(16))) unsigned short ldsl[48 * 72];

    const unsigned short* qb = qs + ((size_t)b * N_ + nb0) * C_ + hg * 192;
    #pragma unroll
    for (int i = 0; i < 6; ++i) {
        int g = (i * 4 + w) * 64;
        int f = g + lane;
        int row = f / 24, sc = f % 24;
        int c = sc ^ (row & 7);
        async16(qb + (size_t)row * C_ + c * 8, ldsq + (size_t)g * 8);
    }
    const float* kvb = kvf + ((size_t)(b * NH_ + hg * 4)) * 2304;
    const float S2 = 0.28867513459481287f;
    int quad = lane >> 4;
    int qrow = w * 16 + (lane & 15);

    for (int hl = 0; hl < 4; ++hl) {
        __syncthreads();
        const float* kvh = kvb + hl * 2304;
        for (int i = t; i < 48 * 64; i += 256) {
            int e = i >> 6, d = i & 63;
            unsigned short h16 = 0, l16 = 0;
            if (d < 48) {
                float v = kvh[e * 48 + d];
                h16 = f2b(v);
                l16 = f2b(v - b2f(h16));
            }
            ldsh[e * 72 + d] = h16;
            ldsl[e * 72 + d] = l16;
        }
        __syncthreads();

        f32x4 acc[3] = {};
        #pragma unroll
        for (int ksb = 0; ksb < 2; ++ksb) {
            int c = hl * 6 + ksb * 4 + quad;
            int cc = c > 23 ? 23 : c;
            int slot = cc ^ (qrow & 7);
            short8 a = *(const short8*)&ldsq[(qrow * 24 + slot) * 8];
            #pragma unroll
            for (int ei = 0; ei < 3; ++ei) {
                int e = ei * 16 + (lane & 15);
                short8 bh = *(const short8*)&ldsh[e * 72 + ksb * 32 + quad * 8];
                short8 bl = *(const short8*)&ldsl[e * 72 + ksb * 32 + quad * 8];
                acc[ei] = __builtin_amdgcn_mfma_f32_16x16x32_bf16(a, bh, acc[ei], 0, 0, 0);
                acc[ei] = __builtin_amdgcn_mfma_f32_16x16x32_bf16(a, bl, acc[ei], 0, 0, 0);
            }
        }
        #pragma unroll
        for (int ei = 0; ei < 3; ++ei) {
            int col = hl * 48 + ei * 16 + (lane & 15);
            int ch = col >> 3, j = col & 7;
            #pragma unroll
            for (int r = 0; r < 4; ++r) {
                int row = w * 16 + quad * 4 + r;
                ldsq[(row * 24 + (ch ^ (row & 7))) * 8 + j] = f2h(spikef(acc[ei][r] * S2));
            }
        }
    }
    __syncthreads();
    unsigned short* ob = as_ + ((size_t)b * N_ + nb0) * C_ + hg * 192;
    #pragma unroll
    for (int i = 0; i < 6; ++i) {
        int f = i * 256 + t;
        int row = f / 24, sc = f % 24;
        int slot = sc ^ (row & 7);
        uint4 d = *(const uint4*)&ldsq[(row * 24 + slot) * 8];
        *(uint4*)(ob + (size_t)row * C_ + sc * 8) = d;
    }
}

// ---------------- K4: out = BN(P @ a_s) -> f32 [b][c][n], LDS-staged coalesced stores ----------------
__global__ __launch_bounds__(256) void k4_pconv(const unsigned short* __restrict__ as_,
                                                const unsigned short* __restrict__ wsp,
                                                P5 pp,
                                                float* __restrict__ out) {
    int gid = blockIdx.x;                      // 768 = 8 xcd * 96
    int xcd = gid & 7, idx = gid >> 3;
    int pairSlot = idx / 3, mt = idx - pairSlot * 3;
    int p = xcd * 32 + pairSlot;
    int ntile = p >> 3, b = p & 7;
    int orow0 = mt * 128;
    int n0 = ntile * 128;
    int t = threadIdx.x, lane = t & 63, wvv = t >> 6;
    int wr = wvv >> 1, wc = wvv & 1;

    __shared__ __attribute__((aligned(16))) char ldsb[33792];
    short* lds = (short*)ldsb;
    const unsigned short* abase = as_ + (size_t)b * CB_;
    const unsigned short* wbase = wsp + (size_t)3 * 384 * KS2;

    f32x4 acc[4][4] = {};
    for (int kk = 0; kk < KS2; kk += 64) {
        if (kk == 384) {
            #pragma unroll
            for (int mi = 0; mi < 4; ++mi)
                #pragma unroll
                for (int ni = 0; ni < 4; ++ni)
                    acc[mi][ni] = acc[mi][ni] * 0.000244140625f;
        }
        int ck = (kk >= 384) ? kk - 384 : kk;
        #pragma unroll
        for (int j = 0; j < 4; ++j) {
            int row = wvv * 32 + j * 8 + (lane >> 3);
            int g = (lane & 7) ^ (row & 7);
            async16(abase + (size_t)(n0 + row) * C_ + ck + g * 8, lds + (wvv * 32 + j * 8) * 64);
        }
        #pragma unroll
        for (int j = 0; j < 4; ++j) {
            int row = wvv * 32 + j * 8 + (lane >> 3);
            int g = (lane & 7) ^ (row & 7);
            async16(wbase + (size_t)(orow0 + row) * KS2 + kk + g * 8, lds + 8192 + (wvv * 32 + j * 8) * 64);
        }
        __syncthreads();
        #pragma unroll
        for (int ksb = 0; ksb < 2; ++ksb) {
            half8 af[4], bfr[4];
            #pragma unroll
            for (int mi = 0; mi < 4; ++mi) {
                int row = wr * 64 + mi * 16 + (lane & 15);
                int s = (ksb * 4 + (lane >> 4)) ^ (row & 7);
                af[mi] = *(const half8*)&lds[row * 64 + s * 8];
            }
            #pragma unroll
            for (int ni = 0; ni < 4; ++ni) {
                int row = wc * 64 + ni * 16 + (lane & 15);
                int s = (ksb * 4 + (lane >> 4)) ^ (row & 7);
                bfr[ni] = *(const half8*)&lds[8192 + row * 64 + s * 8];
            }
            #pragma unroll
            for (int mi = 0; mi < 4; ++mi)
                #pragma unroll
                for (int ni = 0; ni < 4; ++ni)
                    acc[mi][ni] = __builtin_amdgcn_mfma_f32_16x16x32_f16(af[mi], bfr[ni], acc[mi][ni], 0, 0, 0);
        }
        __syncthreads();
    }

    float s_bn[4], t_bn[4];
    #pragma unroll
    for (int ni = 0; ni < 4; ++ni) {
        int o = orow0 + wc * 64 + ni * 16 + (lane & 15);
        float g = pp.g[o], be = pp.be[o], mu = pp.mu[o], va = pp.va[o];
        float s = g / sqrtf(va + 1e-5f);
        s_bn[ni] = s; t_bn[ni] = be - mu * s;
    }
    float* fsm = (float*)ldsb;
    for (int half = 0; half < 2; ++half) {
        __syncthreads();
        if (wc == half) {
            #pragma unroll
            for (int mi = 0; mi < 4; ++mi)
                #pragma unroll
                for (int ni = 0; ni < 4; ++ni) {
                    int ol = ni * 16 + (lane & 15);
                    int nl = wr * 64 + mi * 16 + (lane >> 4) * 4;
                    f32x4 vv;
                    #pragma unroll
                    for (int r = 0; r < 4; ++r)
                        vv[r] = acc[mi][ni][r] * s_bn[ni] + t_bn[ni];
                    *(f32x4*)&fsm[ol * 132 + nl] = vv;
                }
        }
        __syncthreads();
        #pragma unroll
        for (int i = 0; i < 8; ++i) {
            int f = i * 256 + t;
            int o = f >> 5, slot = f & 31;
            f32x4 vv = *(const f32x4*)&fsm[o * 132 + slot * 4];
            *(f32x4*)(out + ((size_t)b * C_ + orow0 + half * 64 + o) * N_ + n0 + slot * 4) = vv;
        }
    }
}

extern "C" void kernel_launch(void* const* d_in, const int* in_sizes, int n_in,
                              void* d_out, int out_size, void* d_ws, size_t ws_size,
                              hipStream_t stream) {
    P5 pq { (const float*)d_in[1],  (const float*)d_in[2],  (const float*)d_in[3],
            (const float*)d_in[4],  (const float*)d_in[5] };
    P5 pk { (const float*)d_in[6],  (const float*)d_in[7],  (const float*)d_in[8],
            (const float*)d_in[9],  (const float*)d_in[10] };
    P5 pv { (const float*)d_in[11], (const float*)d_in[12], (const float*)d_in[13],
            (const float*)d_in[14], (const float*)d_in[15] };
    P5 pp { (const float*)d_in[16], (const float*)d_in[17], (const float*)d_in[18],
            (const float*)d_in[19], (const float*)d_in[20] };
    W4 w4 { pq.w, pk.w, pv.w, pp.w };

    char* ws = (char*)d_ws;
    const size_t S = (size_t)B_ * C_ * N_ * 2;
    unsigned short* xst = (unsigned short*)ws;
    unsigned short* qs  = (unsigned short*)(ws + S);
    unsigned short* ks  = (unsigned short*)(ws + 2 * S + 256);
    unsigned short* vs  = (unsigned short*)(ws + 3 * S + 512);
    float*          kvf = (float*)(ws + 4 * S + 768);
    unsigned short* wsp = (unsigned short*)(ws + 4 * S + 768 + 589824);
    unsigned short* as_ = xst;

    kprep0<<<5376, 256, 0, stream>>>((const float*)d_in[0], xst, w4, wsp);
    k1_qkv<<<2304, 256, 0, stream>>>(xst, wsp, pq, pk, pv, qs, ks, vs);
    k2_kv<<<64, 256, 0, stream>>>(ks, vs, kvf);
    k3_attn<<<1024, 256, 0, stream>>>(qs, kvf, as_);
    k4_pconv<<<768, 256, 0, stream>>>(as_, wsp, pp, (float*)d_out);
}

// Round 10
// 263.909 us; speedup vs baseline: 1.1367x; 1.0184x over previous
//
#include <hip/hip_runtime.h>
#include <stdint.h>

#define B_  8
#define C_  384
#define N_  4096
#define NH_ 8
#define HD_ 48
#define CB_ (C_*N_)
#define KS2 768   // 2 x 384 (scaled-f16 hi/lo split of f32 weights)

typedef __attribute__((ext_vector_type(8))) short short8;
typedef __attribute__((ext_vector_type(8))) _Float16 half8;
typedef __attribute__((ext_vector_type(4))) float f32x4;

struct P5 { const float *w, *g, *be, *mu, *va; };
struct W4 { const float *w0, *w1, *w2, *w3; };

__device__ __forceinline__ float b2f(unsigned short u) {
    union { unsigned int i; float f; } c; c.i = ((unsigned int)u) << 16; return c.f;
}
__device__ __forceinline__ unsigned short f2b(float f) {
    union { float f; unsigned int i; } c; c.f = f;
    return (unsigned short)((c.i + 0x7FFFu + ((c.i >> 16) & 1u)) >> 16);
}
__device__ __forceinline__ unsigned short f2h(float f) {
    union { _Float16 h; unsigned short u; } c; c.h = (_Float16)f; return c.u;
}
__device__ __forceinline__ float spikef(float f) {
    f = fminf(fmaxf(f, 0.0f), 4.0f);
    return rintf(f) * 0.25f;   // round-half-even == np.round
}
__device__ __forceinline__ void async16(const void* g, void* l) {
    __builtin_amdgcn_global_load_lds((const __attribute__((address_space(1))) void*)g,
                                     (__attribute__((address_space(3))) void*)l, 16, 0, 0);
}

// ---------------- Kprep0: [0..767] spike+transpose x (64c x 256n tiles, 1KB-granule reads);
//                  [768..3071] weight split ----------------
__global__ __launch_bounds__(256) void kprep0(const float* __restrict__ x,
                                              unsigned short* __restrict__ xst,
                                              W4 ws4, unsigned short* __restrict__ wsp) {
    int bid = blockIdx.x;
    int t = threadIdx.x;
    __shared__ __attribute__((aligned(16))) unsigned short sm[64 * 260];
    if (bid < 768) {             // ---- x spike+transpose ----
        int n16 = bid & 15, rest = bid >> 4;
        int ct = rest % 6, b = rest / 6;
        int n0 = n16 * 256, c0 = ct * 64;
        int w = t >> 6, l = t & 63;
        const float* xb = x + (size_t)b * CB_;
        #pragma unroll
        for (int it = 0; it < 16; ++it) {
            int r = it * 4 + w;                      // c-row; wave reads 1 KB contiguous
            float4 d = *(const float4*)(xb + (size_t)(c0 + r) * N_ + n0 + l * 4);
            unsigned short v[4];
            v[0] = f2h(spikef(d.x)); v[1] = f2h(spikef(d.y));
            v[2] = f2h(spikef(d.z)); v[3] = f2h(spikef(d.w));
            *(uint2*)&sm[r * 260 + l * 4] = *(const uint2*)v;
        }
        __syncthreads();
        unsigned short* ob = xst + (size_t)b * CB_;
        #pragma unroll
        for (int it = 0; it < 8; ++it) {
            int f = it * 256 + t;
            int n = f >> 3, cs = f & 7;              // 8 lanes/row -> 128 B coalesced stores
            unsigned short v[8];
            #pragma unroll
            for (int j = 0; j < 8; ++j) v[j] = sm[(cs * 8 + j) * 260 + n];
            *(uint4*)(ob + (size_t)(n0 + n) * C_ + c0 + cs * 8) = *(const uint4*)v;
        }
    } else {                     // ---- weight split ----
        int idx = (bid - 768) * 256 + t;           // < 589824
        int mat = idx / 147456, rem = idx % 147456;
        int o = rem / 384, c = rem % 384;
        const float* W = (mat == 0) ? ws4.w0 : (mat == 1) ? ws4.w1 : (mat == 2) ? ws4.w2 : ws4.w3;
        float w = W[o * 384 + c];
        _Float16 hh = (fabsf(w) < 6.103515625e-05f) ? (_Float16)0 : (_Float16)w;
        float r1 = w - (float)hh;                  // exact
        float s  = r1 * 4096.0f;                   // exact (pow2)
        union { _Float16 h; unsigned short u; } ch, cl;
        ch.h = hh; cl.h = (_Float16)s;
        unsigned short* row = wsp + (size_t)mat * 384 * KS2 + (size_t)o * KS2 + c;
        row[0] = cl.u; row[384] = ch.u;
    }
}

// ---------------- K1: fused q/k/v conv+BN+spike GEMM (2-pass scaled-f16), XCD-swizzled ----------------
__global__ __launch_bounds__(256) void k1_qkv(const unsigned short* __restrict__ xst,
                                              const unsigned short* __restrict__ wsp,
                                              P5 pq, P5 pk, P5 pv,
                                              unsigned short* __restrict__ qs,
                                              unsigned short* __restrict__ ks,
                                              unsigned short* __restrict__ vs) {
    int gid = blockIdx.x;
    int xcd = gid & 7, idx = gid >> 3;
    int pairSlot = idx / 9, mt = idx - pairSlot * 9;
    int p = xcd * 32 + pairSlot;
    int ntile = p >> 3, b = p & 7;
    int mat = mt / 3;
    int orow0 = (mt % 3) * 128;
    int n0 = ntile * 128;
    int t = threadIdx.x, lane = t & 63, wvv = t >> 6;
    int wr = wvv >> 1, wc = wvv & 1;

    __shared__ __attribute__((aligned(16))) short lds[17408];
    P5 pp = (mat == 0) ? pq : (mat == 1 ? pk : pv);
    const unsigned short* abase = xst + (size_t)b * CB_;
    const unsigned short* wbase = wsp + (size_t)mat * 384 * KS2;

    f32x4 acc[4][4] = {};
    for (int kk = 0; kk < KS2; kk += 64) {
        if (kk == 384) {
            #pragma unroll
            for (int mi = 0; mi < 4; ++mi)
                #pragma unroll
                for (int ni = 0; ni < 4; ++ni)
                    acc[mi][ni] = acc[mi][ni] * 0.000244140625f;
        }
        int ck = (kk >= 384) ? kk - 384 : kk;
        #pragma unroll
        for (int j = 0; j < 4; ++j) {
            int row = wvv * 32 + j * 8 + (lane >> 3);
            int g = (lane & 7) ^ (row & 7);
            async16(abase + (size_t)(n0 + row) * C_ + ck + g * 8, lds + (wvv * 32 + j * 8) * 64);
        }
        #pragma unroll
        for (int j = 0; j < 4; ++j) {
            int row = wvv * 32 + j * 8 + (lane >> 3);
            int g = (lane & 7) ^ (row & 7);
            async16(wbase + (size_t)(orow0 + row) * KS2 + kk + g * 8, lds + 8192 + (wvv * 32 + j * 8) * 64);
        }
        __syncthreads();
        #pragma unroll
        for (int ksb = 0; ksb < 2; ++ksb) {
            half8 af[4], bfr[4];
            #pragma unroll
            for (int mi = 0; mi < 4; ++mi) {
                int row = wr * 64 + mi * 16 + (lane & 15);
                int s = (ksb * 4 + (lane >> 4)) ^ (row & 7);
                af[mi] = *(const half8*)&lds[row * 64 + s * 8];
            }
            #pragma unroll
            for (int ni = 0; ni < 4; ++ni) {
                int row = wc * 64 + ni * 16 + (lane & 15);
                int s = (ksb * 4 + (lane >> 4)) ^ (row & 7);
                bfr[ni] = *(const half8*)&lds[8192 + row * 64 + s * 8];
            }
            #pragma unroll
            for (int mi = 0; mi < 4; ++mi)
                #pragma unroll
                for (int ni = 0; ni < 4; ++ni)
                    acc[mi][ni] = __builtin_amdgcn_mfma_f32_16x16x32_f16(af[mi], bfr[ni], acc[mi][ni], 0, 0, 0);
        }
        __syncthreads();
    }

    float s_bn[4], t_bn[4];
    #pragma unroll
    for (int ni = 0; ni < 4; ++ni) {
        int o = orow0 + wc * 64 + ni * 16 + (lane & 15);
        float g = pp.g[o], be = pp.be[o], mu = pp.mu[o], va = pp.va[o];
        float s = g / sqrtf(va + 1e-5f);
        s_bn[ni] = s; t_bn[ni] = be - mu * s;
    }
    unsigned short* esm = (unsigned short*)lds;

    if (mat != 0) {  // k,v -> [b][c][n] (bf16)
        #pragma unroll
        for (int mi = 0; mi < 4; ++mi)
            #pragma unroll
            for (int ni = 0; ni < 4; ++ni) {
                int ol = wc * 64 + ni * 16 + (lane & 15);
                int nb = wr * 64 + mi * 16 + (lane >> 4) * 4;
                unsigned short vv[4];
                #pragma unroll
                for (int r = 0; r < 4; ++r)
                    vv[r] = f2b(spikef(acc[mi][ni][r] * s_bn[ni] + t_bn[ni]));
                *(uint2*)&esm[ol * 136 + nb] = *(const uint2*)vv;
            }
        __syncthreads();
        unsigned short* dst = ((mat == 1) ? ks : vs) + (size_t)b * CB_;
        #pragma unroll
        for (int i = 0; i < 8; ++i) {
            int o = (t >> 4) + 16 * i;
            int seg = t & 15;
            uint4 d = *(const uint4*)&esm[o * 136 + seg * 8];
            *(uint4*)(dst + (size_t)(orow0 + o) * N_ + n0 + seg * 8) = d;
        }
    } else {        // q -> [b][n][c] (bf16)
        #pragma unroll
        for (int mi = 0; mi < 4; ++mi)
            #pragma unroll
            for (int ni = 0; ni < 4; ++ni) {
                int ol = wc * 64 + ni * 16 + (lane & 15);
                int nb = wr * 64 + mi * 16 + (lane >> 4) * 4;
                #pragma unroll
                for (int r = 0; r < 4; ++r)
                    esm[(nb + r) * 136 + ol] = f2b(spikef(acc[mi][ni][r] * s_bn[ni] + t_bn[ni]));
            }
        __syncthreads();
        #pragma unroll
        for (int i = 0; i < 8; ++i) {
            int n = (t >> 4) + 16 * i;
            int seg = t & 15;
            uint4 d = *(const uint4*)&esm[n * 136 + seg * 8];
            *(uint4*)(qs + ((size_t)b * N_ + n0 + n) * C_ + orow0 + seg * 8) = d;
        }
    }
}

// ---------------- K2: kv partials per (b,h,quarter); 256 blocks, NO atomics ----------------
__global__ __launch_bounds__(256) void k2_kv(const unsigned short* __restrict__ ks,
                                             const unsigned short* __restrict__ vs,
                                             float* __restrict__ kvp) {
    int id = blockIdx.x;                 // 256 = 64 bh * 4 quarters
    int b = id >> 5, h = (id >> 2) & 7, q4 = id & 3;
    int t = threadIdx.x, lane = t & 63, w = t >> 6;
    const unsigned short* kb = ks + (size_t)b * CB_ + h * HD_ * N_;
    const unsigned short* vb = vs + (size_t)b * CB_ + h * HD_ * N_;
    int nbase = q4 * 1024 + w * 256;

    f32x4 acc[3][3] = {};
    for (int kk = 0; kk < 256; kk += 32) {
        int n = nbase + kk + (lane >> 4) * 8;
        short8 af[3], bfr[3];
        #pragma unroll
        for (int di = 0; di < 3; ++di)
            af[di] = *(const short8*)(kb + (size_t)((lane & 15) + 16 * di) * N_ + n);
        #pragma unroll
        for (int ei = 0; ei < 3; ++ei)
            bfr[ei] = *(const short8*)(vb + (size_t)((lane & 15) + 16 * ei) * N_ + n);
        #pragma unroll
        for (int di = 0; di < 3; ++di)
            #pragma unroll
            for (int ei = 0; ei < 3; ++ei)
                acc[di][ei] = __builtin_amdgcn_mfma_f32_16x16x32_bf16(af[di], bfr[ei], acc[di][ei], 0, 0, 0);
    }
    __shared__ float red[4][48][48];
    #pragma unroll
    for (int di = 0; di < 3; ++di)
        #pragma unroll
        for (int ei = 0; ei < 3; ++ei) {
            int d0 = di * 16 + (lane >> 4) * 4;
            int e = ei * 16 + (lane & 15);
            #pragma unroll
            for (int r = 0; r < 4; ++r) red[w][d0 + r][e] = acc[di][ei][r];
        }
    __syncthreads();
    float* dst = kvp + ((size_t)(b * NH_ + h) * 4 + q4) * 2304;
    for (int i = t; i < 2304; i += 256) {
        int e = i / 48, d = i % 48;
        dst[e * 48 + d] = red[0][d][e] + red[1][d][e] + red[2][d][e] + red[3][d][e];  // exact (1/16 multiples)
    }
}

// ---------------- K3: attn = q @ kv * s2, spike -> a_s f16 [b][n][c] ----------------
// 1024 blocks = 8 b * 64 nt * 2 head-groups; sums the 4 kv partials in its split stage.
__global__ __launch_bounds__(256) void k3_attn(const unsigned short* __restrict__ qs,
                                               const float* __restrict__ kvp,
                                               unsigned short* __restrict__ as_) {
    int id = blockIdx.x;
    int hg = id & 1, nt = (id >> 1) & 63, b = id >> 7;
    int t = threadIdx.x, lane = t & 63, w = t >> 6;
    int nb0 = nt * 64;
    __shared__ __attribute__((aligned(16))) unsigned short ldsq[64 * 24 * 8];
    __shared__ __attribute__((aligned(16))) unsigned short ldsh[48 * 72];
    __shared__ __attribute__((aligned(16))) unsigned short ldsl[48 * 72];

    const unsigned short* qb = qs + ((size_t)b * N_ + nb0) * C_ + hg * 192;
    #pragma unroll
    for (int i = 0; i < 6; ++i) {
        int g = (i * 4 + w) * 64;
        int f = g + lane;
        int row = f / 24, sc = f % 24;
        int c = sc ^ (row & 7);
        async16(qb + (size_t)row * C_ + c * 8, ldsq + (size_t)g * 8);
    }
    const float S2 = 0.28867513459481287f;
    int quad = lane >> 4;
    int qrow = w * 16 + (lane & 15);

    for (int hl = 0; hl < 4; ++hl) {
        __syncthreads();
        const float* kvh = kvp + (size_t)((b * NH_ + hg * 4 + hl) * 4) * 2304;
        for (int i = t; i < 48 * 64; i += 256) {
            int e = i >> 6, d = i & 63;
            unsigned short h16 = 0, l16 = 0;
            if (d < 48) {
                int o = e * 48 + d;
                float v = kvh[o] + kvh[2304 + o] + kvh[4608 + o] + kvh[6912 + o]; // exact
                h16 = f2b(v);
                l16 = f2b(v - b2f(h16));
            }
            ldsh[e * 72 + d] = h16;
            ldsl[e * 72 + d] = l16;
        }
        __syncthreads();

        f32x4 acc[3] = {};
        #pragma unroll
        for (int ksb = 0; ksb < 2; ++ksb) {
            int c = hl * 6 + ksb * 4 + quad;
            int cc = c > 23 ? 23 : c;
            int slot = cc ^ (qrow & 7);
            short8 a = *(const short8*)&ldsq[(qrow * 24 + slot) * 8];
            #pragma unroll
            for (int ei = 0; ei < 3; ++ei) {
                int e = ei * 16 + (lane & 15);
                short8 bh = *(const short8*)&ldsh[e * 72 + ksb * 32 + quad * 8];
                short8 bl = *(const short8*)&ldsl[e * 72 + ksb * 32 + quad * 8];
                acc[ei] = __builtin_amdgcn_mfma_f32_16x16x32_bf16(a, bh, acc[ei], 0, 0, 0);
                acc[ei] = __builtin_amdgcn_mfma_f32_16x16x32_bf16(a, bl, acc[ei], 0, 0, 0);
            }
        }
        #pragma unroll
        for (int ei = 0; ei < 3; ++ei) {
            int col = hl * 48 + ei * 16 + (lane & 15);
            int ch = col >> 3, j = col & 7;
            #pragma unroll
            for (int r = 0; r < 4; ++r) {
                int row = w * 16 + quad * 4 + r;
                ldsq[(row * 24 + (ch ^ (row & 7))) * 8 + j] = f2h(spikef(acc[ei][r] * S2));
            }
        }
    }
    __syncthreads();
    unsigned short* ob = as_ + ((size_t)b * N_ + nb0) * C_ + hg * 192;
    #pragma unroll
    for (int i = 0; i < 6; ++i) {
        int f = i * 256 + t;
        int row = f / 24, sc = f % 24;
        int slot = sc ^ (row & 7);
        uint4 d = *(const uint4*)&ldsq[(row * 24 + slot) * 8];
        *(uint4*)(ob + (size_t)row * C_ + sc * 8) = d;
    }
}

// ---------------- K4: out = BN(P @ a_s) -> f32 [b][c][n], LDS-staged coalesced stores ----------------
__global__ __launch_bounds__(256) void k4_pconv(const unsigned short* __restrict__ as_,
                                                const unsigned short* __restrict__ wsp,
                                                P5 pp,
                                                float* __restrict__ out) {
    int gid = blockIdx.x;                      // 768 = 8 xcd * 96
    int xcd = gid & 7, idx = gid >> 3;
    int pairSlot = idx / 3, mt = idx - pairSlot * 3;
    int p = xcd * 32 + pairSlot;
    int ntile = p >> 3, b = p & 7;
    int orow0 = mt * 128;
    int n0 = ntile * 128;
    int t = threadIdx.x, lane = t & 63, wvv = t >> 6;
    int wr = wvv >> 1, wc = wvv & 1;

    __shared__ __attribute__((aligned(16))) char ldsb[33792];
    short* lds = (short*)ldsb;
    const unsigned short* abase = as_ + (size_t)b * CB_;
    const unsigned short* wbase = wsp + (size_t)3 * 384 * KS2;

    f32x4 acc[4][4] = {};
    for (int kk = 0; kk < KS2; kk += 64) {
        if (kk == 384) {
            #pragma unroll
            for (int mi = 0; mi < 4; ++mi)
                #pragma unroll
                for (int ni = 0; ni < 4; ++ni)
                    acc[mi][ni] = acc[mi][ni] * 0.000244140625f;
        }
        int ck = (kk >= 384) ? kk - 384 : kk;
        #pragma unroll
        for (int j = 0; j < 4; ++j) {
            int row = wvv * 32 + j * 8 + (lane >> 3);
            int g = (lane & 7) ^ (row & 7);
            async16(abase + (size_t)(n0 + row) * C_ + ck + g * 8, lds + (wvv * 32 + j * 8) * 64);
        }
        #pragma unroll
        for (int j = 0; j < 4; ++j) {
            int row = wvv * 32 + j * 8 + (lane >> 3);
            int g = (lane & 7) ^ (row & 7);
            async16(wbase + (size_t)(orow0 + row) * KS2 + kk + g * 8, lds + 8192 + (wvv * 32 + j * 8) * 64);
        }
        __syncthreads();
        #pragma unroll
        for (int ksb = 0; ksb < 2; ++ksb) {
            half8 af[4], bfr[4];
            #pragma unroll
            for (int mi = 0; mi < 4; ++mi) {
                int row = wr * 64 + mi * 16 + (lane & 15);
                int s = (ksb * 4 + (lane >> 4)) ^ (row & 7);
                af[mi] = *(const half8*)&lds[row * 64 + s * 8];
            }
            #pragma unroll
            for (int ni = 0; ni < 4; ++ni) {
                int row = wc * 64 + ni * 16 + (lane & 15);
                int s = (ksb * 4 + (lane >> 4)) ^ (row & 7);
                bfr[ni] = *(const half8*)&lds[8192 + row * 64 + s * 8];
            }
            #pragma unroll
            for (int mi = 0; mi < 4; ++mi)
                #pragma unroll
                for (int ni = 0; ni < 4; ++ni)
                    acc[mi][ni] = __builtin_amdgcn_mfma_f32_16x16x32_f16(af[mi], bfr[ni], acc[mi][ni], 0, 0, 0);
        }
        __syncthreads();
    }

    float s_bn[4], t_bn[4];
    #pragma unroll
    for (int ni = 0; ni < 4; ++ni) {
        int o = orow0 + wc * 64 + ni * 16 + (lane & 15);
        float g = pp.g[o], be = pp.be[o], mu = pp.mu[o], va = pp.va[o];
        float s = g / sqrtf(va + 1e-5f);
        s_bn[ni] = s; t_bn[ni] = be - mu * s;
    }
    float* fsm = (float*)ldsb;
    for (int half = 0; half < 2; ++half) {
        __syncthreads();
        if (wc == half) {
            #pragma unroll
            for (int mi = 0; mi < 4; ++mi)
                #pragma unroll
                for (int ni = 0; ni < 4; ++ni) {
                    int ol = ni * 16 + (lane & 15);
                    int nl = wr * 64 + mi * 16 + (lane >> 4) * 4;
                    f32x4 vv;
                    #pragma unroll
                    for (int r = 0; r < 4; ++r)
                        vv[r] = acc[mi][ni][r] * s_bn[ni] + t_bn[ni];
                    *(f32x4*)&fsm[ol * 132 + nl] = vv;
                }
        }
        __syncthreads();
        #pragma unroll
        for (int i = 0; i < 8; ++i) {
            int f = i * 256 + t;
            int o = f >> 5, slot = f & 31;
            f32x4 vv = *(const f32x4*)&fsm[o * 132 + slot * 4];
            *(f32x4*)(out + ((size_t)b * C_ + orow0 + half * 64 + o) * N_ + n0 + slot * 4) = vv;
        }
    }
}

extern "C" void kernel_launch(void* const* d_in, const int* in_sizes, int n_in,
                              void* d_out, int out_size, void* d_ws, size_t ws_size,
                              hipStream_t stream) {
    P5 pq { (const float*)d_in[1],  (const float*)d_in[2],  (const float*)d_in[3],
            (const float*)d_in[4],  (const float*)d_in[5] };
    P5 pk { (const float*)d_in[6],  (const float*)d_in[7],  (const float*)d_in[8],
            (const float*)d_in[9],  (const float*)d_in[10] };
    P5 pv { (const float*)d_in[11], (const float*)d_in[12], (const float*)d_in[13],
            (const float*)d_in[14], (const float*)d_in[15] };
    P5 pp { (const float*)d_in[16], (const float*)d_in[17], (const float*)d_in[18],
            (const float*)d_in[19], (const float*)d_in[20] };
    W4 w4 { pq.w, pk.w, pv.w, pp.w };

    char* ws = (char*)d_ws;
    const size_t S = (size_t)B_ * C_ * N_ * 2;
    unsigned short* xst = (unsigned short*)ws;
    unsigned short* qs  = (unsigned short*)(ws + S);
    unsigned short* ks  = (unsigned short*)(ws + 2 * S + 256);
    unsigned short* vs  = (unsigned short*)(ws + 3 * S + 512);
    float*          kvp = (float*)(ws + 4 * S + 768);                        // 4*64*2304*4 = 2359296 B
    unsigned short* wsp = (unsigned short*)(ws + 4 * S + 768 + 2359296);     // 2359296 B
    unsigned short* as_ = xst;

    kprep0<<<3072, 256, 0, stream>>>((const float*)d_in[0], xst, w4, wsp);
    k1_qkv<<<2304, 256, 0, stream>>>(xst, wsp, pq, pk, pv, qs, ks, vs);
    k2_kv<<<256, 256, 0, stream>>>(ks, vs, kvp);
    k3_attn<<<1024, 256, 0, stream>>>(qs, kvp, as_);
    k4_pconv<<<768, 256, 0, stream>>>(as_, wsp, pp, (float*)d_out);
}

// Round 11
// 257.816 us; speedup vs baseline: 1.1636x; 1.0236x over previous
//
#include <hip/hip_runtime.h>
#include <stdint.h>

#define B_  8
#define C_  384
#define N_  4096
#define NH_ 8
#define HD_ 48
#define CB_ (C_*N_)
#define KS2 768   // 2 x 384 (scaled-f16 hi/lo split of f32 weights)

typedef __attribute__((ext_vector_type(8))) short short8;
typedef __attribute__((ext_vector_type(8))) _Float16 half8;
typedef __attribute__((ext_vector_type(4))) float f32x4;

struct P5 { const float *w, *g, *be, *mu, *va; };
struct W4 { const float *w0, *w1, *w2, *w3; };

__device__ __forceinline__ float b2f(unsigned short u) {
    union { unsigned int i; float f; } c; c.i = ((unsigned int)u) << 16; return c.f;
}
__device__ __forceinline__ unsigned short f2b(float f) {
    union { float f; unsigned int i; } c; c.f = f;
    return (unsigned short)((c.i + 0x7FFFu + ((c.i >> 16) & 1u)) >> 16);
}
__device__ __forceinline__ unsigned short f2h(float f) {
    union { _Float16 h; unsigned short u; } c; c.h = (_Float16)f; return c.u;
}
__device__ __forceinline__ float spikef(float f) {
    f = fminf(fmaxf(f, 0.0f), 4.0f);
    return rintf(f) * 0.25f;   // round-half-even == np.round
}
__device__ __forceinline__ void async16(const void* g, void* l) {
    __builtin_amdgcn_global_load_lds((const __attribute__((address_space(1))) void*)g,
                                     (__attribute__((address_space(3))) void*)l, 16, 0, 0);
}

// ---------------- Kprep0: [0..767] spike+transpose x (64c x 256n tiles); [768..3071] weight split ----------------
__global__ __launch_bounds__(256) void kprep0(const float* __restrict__ x,
                                              unsigned short* __restrict__ xst,
                                              W4 ws4, unsigned short* __restrict__ wsp) {
    int bid = blockIdx.x;
    int t = threadIdx.x;
    __shared__ __attribute__((aligned(16))) unsigned short sm[64 * 262]; // stride 262 (131 words): 2-way banks
    if (bid < 768) {             // ---- x spike+transpose ----
        int n16 = bid & 15, rest = bid >> 4;
        int ct = rest % 6, b = rest / 6;
        int n0 = n16 * 256, c0 = ct * 64;
        int w = t >> 6, l = t & 63;
        const float* xb = x + (size_t)b * CB_;
        #pragma unroll
        for (int it = 0; it < 16; ++it) {
            int r = it * 4 + w;                      // c-row; wave reads 1 KB contiguous
            float4 d = *(const float4*)(xb + (size_t)(c0 + r) * N_ + n0 + l * 4);
            unsigned short v[4];
            v[0] = f2h(spikef(d.x)); v[1] = f2h(spikef(d.y));
            v[2] = f2h(spikef(d.z)); v[3] = f2h(spikef(d.w));
            *(uint2*)&sm[r * 262 + l * 4] = *(const uint2*)v;
        }
        __syncthreads();
        unsigned short* ob = xst + (size_t)b * CB_;
        #pragma unroll
        for (int it = 0; it < 8; ++it) {
            int f = it * 256 + t;
            int n = f >> 3, cs = f & 7;              // 8 lanes/row -> 128 B coalesced stores
            unsigned short v[8];
            #pragma unroll
            for (int j = 0; j < 8; ++j) v[j] = sm[(cs * 8 + j) * 262 + n];
            *(uint4*)(ob + (size_t)(n0 + n) * C_ + c0 + cs * 8) = *(const uint4*)v;
        }
    } else {                     // ---- weight split ----
        int idx = (bid - 768) * 256 + t;           // < 589824
        int mat = idx / 147456, rem = idx % 147456;
        int o = rem / 384, c = rem % 384;
        const float* W = (mat == 0) ? ws4.w0 : (mat == 1) ? ws4.w1 : (mat == 2) ? ws4.w2 : ws4.w3;
        float w = W[o * 384 + c];
        _Float16 hh = (fabsf(w) < 6.103515625e-05f) ? (_Float16)0 : (_Float16)w;
        float r1 = w - (float)hh;                  // exact
        float s  = r1 * 4096.0f;                   // exact (pow2)
        union { _Float16 h; unsigned short u; } ch, cl;
        ch.h = hh; cl.h = (_Float16)s;
        unsigned short* row = wsp + (size_t)mat * 384 * KS2 + (size_t)o * KS2 + c;
        row[0] = cl.u; row[384] = ch.u;
    }
}

// ---------------- K1: fused q/k/v conv+BN+spike GEMM (2-pass scaled-f16), XCD-swizzled, split grid ----------------
__global__ __launch_bounds__(256) void k1_qkv(const unsigned short* __restrict__ xst,
                                              const unsigned short* __restrict__ wsp,
                                              P5 pq, P5 pk, P5 pv,
                                              unsigned short* __restrict__ qs,
                                              unsigned short* __restrict__ ks,
                                              unsigned short* __restrict__ vs,
                                              int base) {
    int gid = blockIdx.x + base;
    int xcd = gid & 7, idx = gid >> 3;
    int pairSlot = idx / 9, mt = idx - pairSlot * 9;
    int p = xcd * 32 + pairSlot;
    int ntile = p >> 3, b = p & 7;
    int mat = mt / 3;
    int orow0 = (mt % 3) * 128;
    int n0 = ntile * 128;
    int t = threadIdx.x, lane = t & 63, wvv = t >> 6;
    int wr = wvv >> 1, wc = wvv & 1;

    __shared__ __attribute__((aligned(16))) short lds[17408];
    P5 pp = (mat == 0) ? pq : (mat == 1 ? pk : pv);
    const unsigned short* abase = xst + (size_t)b * CB_;
    const unsigned short* wbase = wsp + (size_t)mat * 384 * KS2;

    f32x4 acc[4][4] = {};
    for (int kk = 0; kk < KS2; kk += 64) {
        if (kk == 384) {
            #pragma unroll
            for (int mi = 0; mi < 4; ++mi)
                #pragma unroll
                for (int ni = 0; ni < 4; ++ni)
                    acc[mi][ni] = acc[mi][ni] * 0.000244140625f;
        }
        int ck = (kk >= 384) ? kk - 384 : kk;
        #pragma unroll
        for (int j = 0; j < 4; ++j) {
            int row = wvv * 32 + j * 8 + (lane >> 3);
            int g = (lane & 7) ^ (row & 7);
            async16(abase + (size_t)(n0 + row) * C_ + ck + g * 8, lds + (wvv * 32 + j * 8) * 64);
        }
        #pragma unroll
        for (int j = 0; j < 4; ++j) {
            int row = wvv * 32 + j * 8 + (lane >> 3);
            int g = (lane & 7) ^ (row & 7);
            async16(wbase + (size_t)(orow0 + row) * KS2 + kk + g * 8, lds + 8192 + (wvv * 32 + j * 8) * 64);
        }
        __syncthreads();
        #pragma unroll
        for (int ksb = 0; ksb < 2; ++ksb) {
            half8 af[4], bfr[4];
            #pragma unroll
            for (int mi = 0; mi < 4; ++mi) {
                int row = wr * 64 + mi * 16 + (lane & 15);
                int s = (ksb * 4 + (lane >> 4)) ^ (row & 7);
                af[mi] = *(const half8*)&lds[row * 64 + s * 8];
            }
            #pragma unroll
            for (int ni = 0; ni < 4; ++ni) {
                int row = wc * 64 + ni * 16 + (lane & 15);
                int s = (ksb * 4 + (lane >> 4)) ^ (row & 7);
                bfr[ni] = *(const half8*)&lds[8192 + row * 64 + s * 8];
            }
            #pragma unroll
            for (int mi = 0; mi < 4; ++mi)
                #pragma unroll
                for (int ni = 0; ni < 4; ++ni)
                    acc[mi][ni] = __builtin_amdgcn_mfma_f32_16x16x32_f16(af[mi], bfr[ni], acc[mi][ni], 0, 0, 0);
        }
        __syncthreads();
    }

    float s_bn[4], t_bn[4];
    #pragma unroll
    for (int ni = 0; ni < 4; ++ni) {
        int o = orow0 + wc * 64 + ni * 16 + (lane & 15);
        float g = pp.g[o], be = pp.be[o], mu = pp.mu[o], va = pp.va[o];
        float s = g / sqrtf(va + 1e-5f);
        s_bn[ni] = s; t_bn[ni] = be - mu * s;
    }
    unsigned short* esm = (unsigned short*)lds;

    if (mat != 0) {  // k,v -> [b][c][n] (bf16)
        #pragma unroll
        for (int mi = 0; mi < 4; ++mi)
            #pragma unroll
            for (int ni = 0; ni < 4; ++ni) {
                int ol = wc * 64 + ni * 16 + (lane & 15);
                int nb = wr * 64 + mi * 16 + (lane >> 4) * 4;
                unsigned short vv[4];
                #pragma unroll
                for (int r = 0; r < 4; ++r)
                    vv[r] = f2b(spikef(acc[mi][ni][r] * s_bn[ni] + t_bn[ni]));
                *(uint2*)&esm[ol * 136 + nb] = *(const uint2*)vv;
            }
        __syncthreads();
        unsigned short* dst = ((mat == 1) ? ks : vs) + (size_t)b * CB_;
        #pragma unroll
        for (int i = 0; i < 8; ++i) {
            int o = (t >> 4) + 16 * i;
            int seg = t & 15;
            uint4 d = *(const uint4*)&esm[o * 136 + seg * 8];
            *(uint4*)(dst + (size_t)(orow0 + o) * N_ + n0 + seg * 8) = d;
        }
    } else {        // q -> [b][n][c] (bf16)
        #pragma unroll
        for (int mi = 0; mi < 4; ++mi)
            #pragma unroll
            for (int ni = 0; ni < 4; ++ni) {
                int ol = wc * 64 + ni * 16 + (lane & 15);
                int nb = wr * 64 + mi * 16 + (lane >> 4) * 4;
                #pragma unroll
                for (int r = 0; r < 4; ++r)
                    esm[(nb + r) * 136 + ol] = f2b(spikef(acc[mi][ni][r] * s_bn[ni] + t_bn[ni]));
            }
        __syncthreads();
        #pragma unroll
        for (int i = 0; i < 8; ++i) {
            int n = (t >> 4) + 16 * i;
            int seg = t & 15;
            uint4 d = *(const uint4*)&esm[n * 136 + seg * 8];
            *(uint4*)(qs + ((size_t)b * N_ + n0 + n) * C_ + orow0 + seg * 8) = d;
        }
    }
}

// ---------------- K2: kv partials per (b,h,quarter); 256 blocks, NO atomics ----------------
__global__ __launch_bounds__(256) void k2_kv(const unsigned short* __restrict__ ks,
                                             const unsigned short* __restrict__ vs,
                                             float* __restrict__ kvp) {
    int id = blockIdx.x;                 // 256 = 64 bh * 4 quarters
    int b = id >> 5, h = (id >> 2) & 7, q4 = id & 3;
    int t = threadIdx.x, lane = t & 63, w = t >> 6;
    const unsigned short* kb = ks + (size_t)b * CB_ + h * HD_ * N_;
    const unsigned short* vb = vs + (size_t)b * CB_ + h * HD_ * N_;
    int nbase = q4 * 1024 + w * 256;

    f32x4 acc[3][3] = {};
    for (int kk = 0; kk < 256; kk += 32) {
        int n = nbase + kk + (lane >> 4) * 8;
        short8 af[3], bfr[3];
        #pragma unroll
        for (int di = 0; di < 3; ++di)
            af[di] = *(const short8*)(kb + (size_t)((lane & 15) + 16 * di) * N_ + n);
        #pragma unroll
        for (int ei = 0; ei < 3; ++ei)
            bfr[ei] = *(const short8*)(vb + (size_t)((lane & 15) + 16 * ei) * N_ + n);
        #pragma unroll
        for (int di = 0; di < 3; ++di)
            #pragma unroll
            for (int ei = 0; ei < 3; ++ei)
                acc[di][ei] = __builtin_amdgcn_mfma_f32_16x16x32_bf16(af[di], bfr[ei], acc[di][ei], 0, 0, 0);
    }
    __shared__ float red[4][48][48];
    #pragma unroll
    for (int di = 0; di < 3; ++di)
        #pragma unroll
        for (int ei = 0; ei < 3; ++ei) {
            int d0 = di * 16 + (lane >> 4) * 4;
            int e = ei * 16 + (lane & 15);
            #pragma unroll
            for (int r = 0; r < 4; ++r) red[w][d0 + r][e] = acc[di][ei][r];
        }
    __syncthreads();
    float* dst = kvp + ((size_t)(b * NH_ + h) * 4 + q4) * 2304;
    for (int i = t; i < 2304; i += 256) {
        int e = i / 48, d = i % 48;
        dst[e * 48 + d] = red[0][d][e] + red[1][d][e] + red[2][d][e] + red[3][d][e];  // exact (1/16 multiples)
    }
}

// ---------------- K2b: sum 4 kv partials -> bf16 hi/lo, d padded 48->64 with zeros ----------------
__global__ __launch_bounds__(256) void k2b_split(const float* __restrict__ kvp,
                                                 unsigned short* __restrict__ hi,
                                                 unsigned short* __restrict__ lo) {
    int i = blockIdx.x * 256 + threadIdx.x;      // 64*48*64 = 196608
    if (i >= 196608) return;
    int d = i & 63; int rest = i >> 6;           // rest = bh*48 + e
    int bh = rest / 48, e = rest % 48;
    unsigned short h16 = 0, l16 = 0;
    if (d < 48) {
        const float* kvh = kvp + (size_t)bh * 4 * 2304;
        int o = e * 48 + d;
        float v = kvh[o] + kvh[2304 + o] + kvh[4608 + o] + kvh[6912 + o]; // exact, same order as before
        h16 = f2b(v);
        l16 = f2b(v - b2f(h16));                 // hi+lo == v exactly
    }
    hi[i] = h16; lo[i] = l16;
}

// ---------------- K3: attn = q @ kv * s2, spike -> a_s f16 [b][n][c] ----------------
// 1024 blocks = 8 b * 64 nt * 2 head-groups; kv hi/lo staged via 16B vector loads.
__global__ __launch_bounds__(256) void k3_attn(const unsigned short* __restrict__ qs,
                                               const unsigned short* __restrict__ hig,
                                               const unsigned short* __restrict__ log,
                                               unsigned short* __restrict__ as_) {
    int id = blockIdx.x;
    int hg = id & 1, nt = (id >> 1) & 63, b = id >> 7;
    int t = threadIdx.x, lane = t & 63, w = t >> 6;
    int nb0 = nt * 64;
    __shared__ __attribute__((aligned(16))) unsigned short ldsq[64 * 24 * 8];
    __shared__ __attribute__((aligned(16))) unsigned short ldsh[48 * 72];  // [e][72-pad d], cols 48-63 zero
    __shared__ __attribute__((aligned(16))) unsigned short ldsl[48 * 72];

    const unsigned short* qb = qs + ((size_t)b * N_ + nb0) * C_ + hg * 192;
    #pragma unroll
    for (int i = 0; i < 6; ++i) {
        int g = (i * 4 + w) * 64;
        int f = g + lane;
        int row = f / 24, sc = f % 24;
        int c = sc ^ (row & 7);
        async16(qb + (size_t)row * C_ + c * 8, ldsq + (size_t)g * 8);
    }
    const float S2 = 0.28867513459481287f;
    int quad = lane >> 4;
    int qrow = w * 16 + (lane & 15);
    int bh4 = b * NH_ + hg * 4;

    for (int hl = 0; hl < 4; ++hl) {
        __syncthreads();
        // stage kv hi/lo: 48 e x 8 chunks x 2 buffers = 768 16B-loads (incl. zero pad cols)
        #pragma unroll
        for (int it = 0; it < 3; ++it) {
            int i = it * 256 + t;                  // < 768
            int which = i >> 8 == 0 ? 0 : (i >= 384 ? 1 : 0);
            which = (i >= 384) ? 1 : 0;
            int c = (i >= 384) ? i - 384 : i;      // < 384
            int e = c >> 3, ch = c & 7;
            const unsigned short* src = ((which == 0) ? hig : log) + ((size_t)(bh4 + hl) * 48 + e) * 64 + ch * 8;
            uint4 d4 = *(const uint4*)src;
            unsigned short* dst = (which == 0) ? ldsh : ldsl;
            *(uint4*)&dst[e * 72 + ch * 8] = d4;
        }
        __syncthreads();

        f32x4 acc[3] = {};
        #pragma unroll
        for (int ksb = 0; ksb < 2; ++ksb) {
            int c = hl * 6 + ksb * 4 + quad;
            int cc = c > 23 ? 23 : c;
            int slot = cc ^ (qrow & 7);
            short8 a = *(const short8*)&ldsq[(qrow * 24 + slot) * 8];
            #pragma unroll
            for (int ei = 0; ei < 3; ++ei) {
                int e = ei * 16 + (lane & 15);
                short8 bh = *(const short8*)&ldsh[e * 72 + ksb * 32 + quad * 8];
                short8 bl = *(const short8*)&ldsl[e * 72 + ksb * 32 + quad * 8];
                acc[ei] = __builtin_amdgcn_mfma_f32_16x16x32_bf16(a, bh, acc[ei], 0, 0, 0);
                acc[ei] = __builtin_amdgcn_mfma_f32_16x16x32_bf16(a, bl, acc[ei], 0, 0, 0);
            }
        }
        #pragma unroll
        for (int ei = 0; ei < 3; ++ei) {
            int col = hl * 48 + ei * 16 + (lane & 15);
            int ch = col >> 3, j = col & 7;
            #pragma unroll
            for (int r = 0; r < 4; ++r) {
                int row = w * 16 + quad * 4 + r;
                ldsq[(row * 24 + (ch ^ (row & 7))) * 8 + j] = f2h(spikef(acc[ei][r] * S2));
            }
        }
    }
    __syncthreads();
    unsigned short* ob = as_ + ((size_t)b * N_ + nb0) * C_ + hg * 192;
    #pragma unroll
    for (int i = 0; i < 6; ++i) {
        int f = i * 256 + t;
        int row = f / 24, sc = f % 24;
        int slot = sc ^ (row & 7);
        uint4 d = *(const uint4*)&ldsq[(row * 24 + slot) * 8];
        *(uint4*)(ob + (size_t)row * C_ + sc * 8) = d;
    }
}

// ---------------- K4: out = BN(P @ a_s) -> f32 [b][c][n], LDS-staged coalesced stores ----------------
__global__ __launch_bounds__(256) void k4_pconv(const unsigned short* __restrict__ as_,
                                                const unsigned short* __restrict__ wsp,
                                                P5 pp,
                                                float* __restrict__ out) {
    int gid = blockIdx.x;                      // 768 = 8 xcd * 96
    int xcd = gid & 7, idx = gid >> 3;
    int pairSlot = idx / 3, mt = idx - pairSlot * 3;
    int p = xcd * 32 + pairSlot;
    int ntile = p >> 3, b = p & 7;
    int orow0 = mt * 128;
    int n0 = ntile * 128;
    int t = threadIdx.x, lane = t & 63, wvv = t >> 6;
    int wr = wvv >> 1, wc = wvv & 1;

    __shared__ __attribute__((aligned(16))) char ldsb[33792];
    short* lds = (short*)ldsb;
    const unsigned short* abase = as_ + (size_t)b * CB_;
    const unsigned short* wbase = wsp + (size_t)3 * 384 * KS2;

    f32x4 acc[4][4] = {};
    for (int kk = 0; kk < KS2; kk += 64) {
        if (kk == 384) {
            #pragma unroll
            for (int mi = 0; mi < 4; ++mi)
                #pragma unroll
                for (int ni = 0; ni < 4; ++ni)
                    acc[mi][ni] = acc[mi][ni] * 0.000244140625f;
        }
        int ck = (kk >= 384) ? kk - 384 : kk;
        #pragma unroll
        for (int j = 0; j < 4; ++j) {
            int row = wvv * 32 + j * 8 + (lane >> 3);
            int g = (lane & 7) ^ (row & 7);
            async16(abase + (size_t)(n0 + row) * C_ + ck + g * 8, lds + (wvv * 32 + j * 8) * 64);
        }
        #pragma unroll
        for (int j = 0; j < 4; ++j) {
            int row = wvv * 32 + j * 8 + (lane >> 3);
            int g = (lane & 7) ^ (row & 7);
            async16(wbase + (size_t)(orow0 + row) * KS2 + kk + g * 8, lds + 8192 + (wvv * 32 + j * 8) * 64);
        }
        __syncthreads();
        #pragma unroll
        for (int ksb = 0; ksb < 2; ++ksb) {
            half8 af[4], bfr[4];
            #pragma unroll
            for (int mi = 0; mi < 4; ++mi) {
                int row = wr * 64 + mi * 16 + (lane & 15);
                int s = (ksb * 4 + (lane >> 4)) ^ (row & 7);
                af[mi] = *(const half8*)&lds[row * 64 + s * 8];
            }
            #pragma unroll
            for (int ni = 0; ni < 4; ++ni) {
                int row = wc * 64 + ni * 16 + (lane & 15);
                int s = (ksb * 4 + (lane >> 4)) ^ (row & 7);
                bfr[ni] = *(const half8*)&lds[8192 + row * 64 + s * 8];
            }
            #pragma unroll
            for (int mi = 0; mi < 4; ++mi)
                #pragma unroll
                for (int ni = 0; ni < 4; ++ni)
                    acc[mi][ni] = __builtin_amdgcn_mfma_f32_16x16x32_f16(af[mi], bfr[ni], acc[mi][ni], 0, 0, 0);
        }
        __syncthreads();
    }

    float s_bn[4], t_bn[4];
    #pragma unroll
    for (int ni = 0; ni < 4; ++ni) {
        int o = orow0 + wc * 64 + ni * 16 + (lane & 15);
        float g = pp.g[o], be = pp.be[o], mu = pp.mu[o], va = pp.va[o];
        float s = g / sqrtf(va + 1e-5f);
        s_bn[ni] = s; t_bn[ni] = be - mu * s;
    }
    float* fsm = (float*)ldsb;
    for (int half = 0; half < 2; ++half) {
        __syncthreads();
        if (wc == half) {
            #pragma unroll
            for (int mi = 0; mi < 4; ++mi)
                #pragma unroll
                for (int ni = 0; ni < 4; ++ni) {
                    int ol = ni * 16 + (lane & 15);
                    int nl = wr * 64 + mi * 16 + (lane >> 4) * 4;
                    f32x4 vv;
                    #pragma unroll
                    for (int r = 0; r < 4; ++r)
                        vv[r] = acc[mi][ni][r] * s_bn[ni] + t_bn[ni];
                    *(f32x4*)&fsm[ol * 132 + nl] = vv;
                }
        }
        __syncthreads();
        #pragma unroll
        for (int i = 0; i < 8; ++i) {
            int f = i * 256 + t;
            int o = f >> 5, slot = f & 31;
            f32x4 vv = *(const f32x4*)&fsm[o * 132 + slot * 4];
            *(f32x4*)(out + ((size_t)b * C_ + orow0 + half * 64 + o) * N_ + n0 + slot * 4) = vv;
        }
    }
}

extern "C" void kernel_launch(void* const* d_in, const int* in_sizes, int n_in,
                              void* d_out, int out_size, void* d_ws, size_t ws_size,
                              hipStream_t stream) {
    P5 pq { (const float*)d_in[1],  (const float*)d_in[2],  (const float*)d_in[3],
            (const float*)d_in[4],  (const float*)d_in[5] };
    P5 pk { (const float*)d_in[6],  (const float*)d_in[7],  (const float*)d_in[8],
            (const float*)d_in[9],  (const float*)d_in[10] };
    P5 pv { (const float*)d_in[11], (const float*)d_in[12], (const float*)d_in[13],
            (const float*)d_in[14], (const float*)d_in[15] };
    P5 pp { (const float*)d_in[16], (const float*)d_in[17], (const float*)d_in[18],
            (const float*)d_in[19], (const float*)d_in[20] };
    W4 w4 { pq.w, pk.w, pv.w, pp.w };

    char* ws = (char*)d_ws;
    const size_t S = (size_t)B_ * C_ * N_ * 2;
    unsigned short* xst = (unsigned short*)ws;
    unsigned short* qs  = (unsigned short*)(ws + S);
    unsigned short* ks  = (unsigned short*)(ws + 2 * S + 256);
    unsigned short* vs  = (unsigned short*)(ws + 3 * S + 512);
    float*          kvp = (float*)(ws + 4 * S + 768);                        // 2359296 B
    unsigned short* hig = (unsigned short*)(ws + 4 * S + 768 + 2359296);     // 393216 B
    unsigned short* log = (unsigned short*)(ws + 4 * S + 768 + 2359296 + 393216);
    unsigned short* wsp = (unsigned short*)(ws + 4 * S + 768 + 2359296 + 2 * 393216); // 2359296 B
    unsigned short* as_ = xst;

    kprep0<<<3072, 256, 0, stream>>>((const float*)d_in[0], xst, w4, wsp);
    k1_qkv<<<1152, 256, 0, stream>>>(xst, wsp, pq, pk, pv, qs, ks, vs, 0);
    k1_qkv<<<1152, 256, 0, stream>>>(xst, wsp, pq, pk, pv, qs, ks, vs, 1152);
    k2_kv<<<256, 256, 0, stream>>>(ks, vs, kvp);
    k2b_split<<<768, 256, 0, stream>>>(kvp, hig, log);
    k3_attn<<<1024, 256, 0, stream>>>(qs, hig, log, as_);
    k4_pconv<<<768, 256, 0, stream>>>(as_, wsp, pp, (float*)d_out);
}

// Round 12
// 239.875 us; speedup vs baseline: 1.2506x; 1.0748x over previous
//
#include <hip/hip_runtime.h>
#include <stdint.h>

#define B_  8
#define C_  384
#define N_  4096
#define NH_ 8
#define HD_ 48
#define CB_ (C_*N_)
#define KS2 768   // 2 x 384 (scaled-f16 hi/lo split of f32 weights)

typedef __attribute__((ext_vector_type(8))) short short8;
typedef __attribute__((ext_vector_type(8))) _Float16 half8;
typedef __attribute__((ext_vector_type(4))) float f32x4;

struct P5 { const float *w, *g, *be, *mu, *va; };
struct W4 { const float *w0, *w1, *w2, *w3; };

__device__ __forceinline__ float b2f(unsigned short u) {
    union { unsigned int i; float f; } c; c.i = ((unsigned int)u) << 16; return c.f;
}
__device__ __forceinline__ unsigned short f2b(float f) {
    union { float f; unsigned int i; } c; c.f = f;
    return (unsigned short)((c.i + 0x7FFFu + ((c.i >> 16) & 1u)) >> 16);
}
__device__ __forceinline__ unsigned short f2h(float f) {
    union { _Float16 h; unsigned short u; } c; c.h = (_Float16)f; return c.u;
}
__device__ __forceinline__ float spikef(float f) {
    f = fminf(fmaxf(f, 0.0f), 4.0f);
    return rintf(f) * 0.25f;   // round-half-even == np.round
}
__device__ __forceinline__ void async16(const void* g, void* l) {
    __builtin_amdgcn_global_load_lds((const __attribute__((address_space(1))) void*)g,
                                     (__attribute__((address_space(3))) void*)l, 16, 0, 0);
}

// ---------------- Kprep0: [0..767] spike+transpose x (64c x 256n tiles); [768..1343] weight split x4 ----------------
__global__ __launch_bounds__(256) void kprep0(const float* __restrict__ x,
                                              unsigned short* __restrict__ xst,
                                              W4 ws4, unsigned short* __restrict__ wsp) {
    int bid = blockIdx.x;
    int t = threadIdx.x;
    __shared__ __attribute__((aligned(16))) unsigned short sm[64 * 262];
    if (bid < 768) {             // ---- x spike+transpose ----
        int n16 = bid & 15, rest = bid >> 4;
        int ct = rest % 6, b = rest / 6;
        int n0 = n16 * 256, c0 = ct * 64;
        int w = t >> 6, l = t & 63;
        const float* xb = x + (size_t)b * CB_;
        #pragma unroll
        for (int it = 0; it < 16; ++it) {
            int r = it * 4 + w;                      // c-row; wave reads 1 KB contiguous
            float4 d = *(const float4*)(xb + (size_t)(c0 + r) * N_ + n0 + l * 4);
            unsigned short v[4];
            v[0] = f2h(spikef(d.x)); v[1] = f2h(spikef(d.y));
            v[2] = f2h(spikef(d.z)); v[3] = f2h(spikef(d.w));
            *(uint2*)&sm[r * 262 + l * 4] = *(const uint2*)v;
        }
        __syncthreads();
        unsigned short* ob = xst + (size_t)b * CB_;
        #pragma unroll
        for (int it = 0; it < 8; ++it) {
            int f = it * 256 + t;
            int n = f >> 3, cs = f & 7;              // 8 lanes/row -> 128 B coalesced stores
            unsigned short v[8];
            #pragma unroll
            for (int j = 0; j < 8; ++j) v[j] = sm[(cs * 8 + j) * 262 + n];
            *(uint4*)(ob + (size_t)(n0 + n) * C_ + c0 + cs * 8) = *(const uint4*)v;
        }
    } else {                     // ---- weight split, 4 elems/thread ----
        int flat4 = (bid - 768) * 256 + t;         // < 147456
        int mat = flat4 / 36864, rem = flat4 % 36864;
        int o = rem / 96, c = (rem % 96) * 4;
        const float* W = (mat == 0) ? ws4.w0 : (mat == 1) ? ws4.w1 : (mat == 2) ? ws4.w2 : ws4.w3;
        float4 wv = *(const float4*)(W + (size_t)o * 384 + c);
        float wa[4] = { wv.x, wv.y, wv.z, wv.w };
        unsigned short hi4[4], lo4[4];
        #pragma unroll
        for (int j = 0; j < 4; ++j) {
            float w = wa[j];
            _Float16 hh = (fabsf(w) < 6.103515625e-05f) ? (_Float16)0 : (_Float16)w;
            float r1 = w - (float)hh;              // exact
            float s  = r1 * 4096.0f;               // exact (pow2)
            union { _Float16 h; unsigned short u; } ch, cl;
            ch.h = hh; cl.h = (_Float16)s;
            hi4[j] = ch.u; lo4[j] = cl.u;
        }
        unsigned short* row = wsp + (size_t)mat * 384 * KS2 + (size_t)o * KS2 + c;
        *(uint2*)row = *(const uint2*)lo4;
        *(uint2*)(row + 384) = *(const uint2*)hi4;
    }
}

// ---------------- K1: fused q/k/v conv+BN+spike GEMM (2-pass scaled-f16), XCD-swizzled ----------------
__global__ __launch_bounds__(256) void k1_qkv(const unsigned short* __restrict__ xst,
                                              const unsigned short* __restrict__ wsp,
                                              P5 pq, P5 pk, P5 pv,
                                              unsigned short* __restrict__ qs,
                                              unsigned short* __restrict__ ks,
                                              unsigned short* __restrict__ vs) {
    int gid = blockIdx.x;
    int xcd = gid & 7, idx = gid >> 3;
    int pairSlot = idx / 9, mt = idx - pairSlot * 9;
    int p = xcd * 32 + pairSlot;
    int ntile = p >> 3, b = p & 7;
    int mat = mt / 3;
    int orow0 = (mt % 3) * 128;
    int n0 = ntile * 128;
    int t = threadIdx.x, lane = t & 63, wvv = t >> 6;
    int wr = wvv >> 1, wc = wvv & 1;

    __shared__ __attribute__((aligned(16))) short lds[17408];
    P5 pp = (mat == 0) ? pq : (mat == 1 ? pk : pv);
    const unsigned short* abase = xst + (size_t)b * CB_;
    const unsigned short* wbase = wsp + (size_t)mat * 384 * KS2;

    f32x4 acc[4][4] = {};
    for (int kk = 0; kk < KS2; kk += 64) {
        if (kk == 384) {
            #pragma unroll
            for (int mi = 0; mi < 4; ++mi)
                #pragma unroll
                for (int ni = 0; ni < 4; ++ni)
                    acc[mi][ni] = acc[mi][ni] * 0.000244140625f;
        }
        int ck = (kk >= 384) ? kk - 384 : kk;
        #pragma unroll
        for (int j = 0; j < 4; ++j) {
            int row = wvv * 32 + j * 8 + (lane >> 3);
            int g = (lane & 7) ^ (row & 7);
            async16(abase + (size_t)(n0 + row) * C_ + ck + g * 8, lds + (wvv * 32 + j * 8) * 64);
        }
        #pragma unroll
        for (int j = 0; j < 4; ++j) {
            int row = wvv * 32 + j * 8 + (lane >> 3);
            int g = (lane & 7) ^ (row & 7);
            async16(wbase + (size_t)(orow0 + row) * KS2 + kk + g * 8, lds + 8192 + (wvv * 32 + j * 8) * 64);
        }
        __syncthreads();
        #pragma unroll
        for (int ksb = 0; ksb < 2; ++ksb) {
            half8 af[4], bfr[4];
            #pragma unroll
            for (int mi = 0; mi < 4; ++mi) {
                int row = wr * 64 + mi * 16 + (lane & 15);
                int s = (ksb * 4 + (lane >> 4)) ^ (row & 7);
                af[mi] = *(const half8*)&lds[row * 64 + s * 8];
            }
            #pragma unroll
            for (int ni = 0; ni < 4; ++ni) {
                int row = wc * 64 + ni * 16 + (lane & 15);
                int s = (ksb * 4 + (lane >> 4)) ^ (row & 7);
                bfr[ni] = *(const half8*)&lds[8192 + row * 64 + s * 8];
            }
            #pragma unroll
            for (int mi = 0; mi < 4; ++mi)
                #pragma unroll
                for (int ni = 0; ni < 4; ++ni)
                    acc[mi][ni] = __builtin_amdgcn_mfma_f32_16x16x32_f16(af[mi], bfr[ni], acc[mi][ni], 0, 0, 0);
        }
        __syncthreads();
    }

    float s_bn[4], t_bn[4];
    #pragma unroll
    for (int ni = 0; ni < 4; ++ni) {
        int o = orow0 + wc * 64 + ni * 16 + (lane & 15);
        float g = pp.g[o], be = pp.be[o], mu = pp.mu[o], va = pp.va[o];
        float s = g / sqrtf(va + 1e-5f);
        s_bn[ni] = s; t_bn[ni] = be - mu * s;
    }
    unsigned short* esm = (unsigned short*)lds;

    if (mat != 0) {  // k,v -> [b][c][n] (bf16)
        #pragma unroll
        for (int mi = 0; mi < 4; ++mi)
            #pragma unroll
            for (int ni = 0; ni < 4; ++ni) {
                int ol = wc * 64 + ni * 16 + (lane & 15);
                int nb = wr * 64 + mi * 16 + (lane >> 4) * 4;
                unsigned short vv[4];
                #pragma unroll
                for (int r = 0; r < 4; ++r)
                    vv[r] = f2b(spikef(acc[mi][ni][r] * s_bn[ni] + t_bn[ni]));
                *(uint2*)&esm[ol * 136 + nb] = *(const uint2*)vv;
            }
        __syncthreads();
        unsigned short* dst = ((mat == 1) ? ks : vs) + (size_t)b * CB_;
        #pragma unroll
        for (int i = 0; i < 8; ++i) {
            int o = (t >> 4) + 16 * i;
            int seg = t & 15;
            uint4 d = *(const uint4*)&esm[o * 136 + seg * 8];
            *(uint4*)(dst + (size_t)(orow0 + o) * N_ + n0 + seg * 8) = d;
        }
    } else {        // q -> [b][n][c] (bf16)
        #pragma unroll
        for (int mi = 0; mi < 4; ++mi)
            #pragma unroll
            for (int ni = 0; ni < 4; ++ni) {
                int ol = wc * 64 + ni * 16 + (lane & 15);
                int nb = wr * 64 + mi * 16 + (lane >> 4) * 4;
                #pragma unroll
                for (int r = 0; r < 4; ++r)
                    esm[(nb + r) * 136 + ol] = f2b(spikef(acc[mi][ni][r] * s_bn[ni] + t_bn[ni]));
            }
        __syncthreads();
        #pragma unroll
        for (int i = 0; i < 8; ++i) {
            int n = (t >> 4) + 16 * i;
            int seg = t & 15;
            uint4 d = *(const uint4*)&esm[n * 136 + seg * 8];
            *(uint4*)(qs + ((size_t)b * N_ + n0 + n) * C_ + orow0 + seg * 8) = d;
        }
    }
}

// ---------------- K2: kv partials per (b,h,quarter); 256 blocks, NO atomics ----------------
__global__ __launch_bounds__(256) void k2_kv(const unsigned short* __restrict__ ks,
                                             const unsigned short* __restrict__ vs,
                                             float* __restrict__ kvp) {
    int id = blockIdx.x;                 // 256 = 64 bh * 4 quarters
    int b = id >> 5, h = (id >> 2) & 7, q4 = id & 3;
    int t = threadIdx.x, lane = t & 63, w = t >> 6;
    const unsigned short* kb = ks + (size_t)b * CB_ + h * HD_ * N_;
    const unsigned short* vb = vs + (size_t)b * CB_ + h * HD_ * N_;
    int nbase = q4 * 1024 + w * 256;

    f32x4 acc[3][3] = {};
    for (int kk = 0; kk < 256; kk += 32) {
        int n = nbase + kk + (lane >> 4) * 8;
        short8 af[3], bfr[3];
        #pragma unroll
        for (int di = 0; di < 3; ++di)
            af[di] = *(const short8*)(kb + (size_t)((lane & 15) + 16 * di) * N_ + n);
        #pragma unroll
        for (int ei = 0; ei < 3; ++ei)
            bfr[ei] = *(const short8*)(vb + (size_t)((lane & 15) + 16 * ei) * N_ + n);
        #pragma unroll
        for (int di = 0; di < 3; ++di)
            #pragma unroll
            for (int ei = 0; ei < 3; ++ei)
                acc[di][ei] = __builtin_amdgcn_mfma_f32_16x16x32_bf16(af[di], bfr[ei], acc[di][ei], 0, 0, 0);
    }
    __shared__ float red[4][48][48];
    #pragma unroll
    for (int di = 0; di < 3; ++di)
        #pragma unroll
        for (int ei = 0; ei < 3; ++ei) {
            int d0 = di * 16 + (lane >> 4) * 4;
            int e = ei * 16 + (lane & 15);
            #pragma unroll
            for (int r = 0; r < 4; ++r) red[w][d0 + r][e] = acc[di][ei][r];
        }
    __syncthreads();
    float* dst = kvp + ((size_t)(b * NH_ + h) * 4 + q4) * 2304;
    for (int i = t; i < 2304; i += 256) {
        int e = i / 48, d = i % 48;
        dst[e * 48 + d] = red[0][d][e] + red[1][d][e] + red[2][d][e] + red[3][d][e];  // exact (1/16 multiples)
    }
}

// ---------------- K2b: sum 4 kv partials -> bf16 hi/lo, d padded 48->64 with zeros ----------------
__global__ __launch_bounds__(256) void k2b_split(const float* __restrict__ kvp,
                                                 unsigned short* __restrict__ hi,
                                                 unsigned short* __restrict__ lo) {
    int i = blockIdx.x * 256 + threadIdx.x;      // 64*48*64 = 196608
    if (i >= 196608) return;
    int d = i & 63; int rest = i >> 6;           // rest = bh*48 + e
    int bh = rest / 48, e = rest % 48;
    unsigned short h16 = 0, l16 = 0;
    if (d < 48) {
        const float* kvh = kvp + (size_t)bh * 4 * 2304;
        int o = e * 48 + d;
        float v = kvh[o] + kvh[2304 + o] + kvh[4608 + o] + kvh[6912 + o]; // exact
        h16 = f2b(v);
        l16 = f2b(v - b2f(h16));                 // hi+lo == v exactly
    }
    hi[i] = h16; lo[i] = l16;
}

// ---------------- K3: attn = q @ kv * s2, spike -> a_s f16 [b][n][c] ----------------
__global__ __launch_bounds__(256) void k3_attn(const unsigned short* __restrict__ qs,
                                               const unsigned short* __restrict__ hig,
                                               const unsigned short* __restrict__ log,
                                               unsigned short* __restrict__ as_) {
    int id = blockIdx.x;
    int hg = id & 1, nt = (id >> 1) & 63, b = id >> 7;
    int t = threadIdx.x, lane = t & 63, w = t >> 6;
    int nb0 = nt * 64;
    __shared__ __attribute__((aligned(16))) unsigned short ldsq[64 * 24 * 8];
    __shared__ __attribute__((aligned(16))) unsigned short ldsh[48 * 72];
    __shared__ __attribute__((aligned(16))) unsigned short ldsl[48 * 72];

    const unsigned short* qb = qs + ((size_t)b * N_ + nb0) * C_ + hg * 192;
    #pragma unroll
    for (int i = 0; i < 6; ++i) {
        int g = (i * 4 + w) * 64;
        int f = g + lane;
        int row = f / 24, sc = f % 24;
        int c = sc ^ (row & 7);
        async16(qb + (size_t)row * C_ + c * 8, ldsq + (size_t)g * 8);
    }
    const float S2 = 0.28867513459481287f;
    int quad = lane >> 4;
    int qrow = w * 16 + (lane & 15);
    int bh4 = b * NH_ + hg * 4;

    for (int hl = 0; hl < 4; ++hl) {
        __syncthreads();
        #pragma unroll
        for (int it = 0; it < 3; ++it) {
            int i = it * 256 + t;                  // < 768
            int which = (i >= 384) ? 1 : 0;
            int c = (i >= 384) ? i - 384 : i;      // < 384
            int e = c >> 3, ch = c & 7;
            const unsigned short* src = ((which == 0) ? hig : log) + ((size_t)(bh4 + hl) * 48 + e) * 64 + ch * 8;
            uint4 d4 = *(const uint4*)src;
            unsigned short* dst = (which == 0) ? ldsh : ldsl;
            *(uint4*)&dst[e * 72 + ch * 8] = d4;
        }
        __syncthreads();

        f32x4 acc[3] = {};
        #pragma unroll
        for (int ksb = 0; ksb < 2; ++ksb) {
            int c = hl * 6 + ksb * 4 + quad;
            int cc = c > 23 ? 23 : c;
            int slot = cc ^ (qrow & 7);
            short8 a = *(const short8*)&ldsq[(qrow * 24 + slot) * 8];
            #pragma unroll
            for (int ei = 0; ei < 3; ++ei) {
                int e = ei * 16 + (lane & 15);
                short8 bh = *(const short8*)&ldsh[e * 72 + ksb * 32 + quad * 8];
                short8 bl = *(const short8*)&ldsl[e * 72 + ksb * 32 + quad * 8];
                acc[ei] = __builtin_amdgcn_mfma_f32_16x16x32_bf16(a, bh, acc[ei], 0, 0, 0);
                acc[ei] = __builtin_amdgcn_mfma_f32_16x16x32_bf16(a, bl, acc[ei], 0, 0, 0);
            }
        }
        #pragma unroll
        for (int ei = 0; ei < 3; ++ei) {
            int col = hl * 48 + ei * 16 + (lane & 15);
            int ch = col >> 3, j = col & 7;
            #pragma unroll
            for (int r = 0; r < 4; ++r) {
                int row = w * 16 + quad * 4 + r;
                ldsq[(row * 24 + (ch ^ (row & 7))) * 8 + j] = f2h(spikef(acc[ei][r] * S2));
            }
        }
    }
    __syncthreads();
    unsigned short* ob = as_ + ((size_t)b * N_ + nb0) * C_ + hg * 192;
    #pragma unroll
    for (int i = 0; i < 6; ++i) {
        int f = i * 256 + t;
        int row = f / 24, sc = f % 24;
        int slot = sc ^ (row & 7);
        uint4 d = *(const uint4*)&ldsq[(row * 24 + slot) * 8];
        *(uint4*)(ob + (size_t)row * C_ + sc * 8) = d;
    }
}

// ---------------- K4: out = BN(P_hi @ a_s) -> f32 [b][c][n], SINGLE f16-hi pass ----------------
// lo-term bound ~2e-3 absolute << 1.37e-2 threshold (no spike after this conv)
__global__ __launch_bounds__(256) void k4_pconv(const unsigned short* __restrict__ as_,
                                                const unsigned short* __restrict__ wsp,
                                                P5 pp,
                                                float* __restrict__ out) {
    int gid = blockIdx.x;                      // 768 = 8 xcd * 96
    int xcd = gid & 7, idx = gid >> 3;
    int pairSlot = idx / 3, mt = idx - pairSlot * 3;
    int p = xcd * 32 + pairSlot;
    int ntile = p >> 3, b = p & 7;
    int orow0 = mt * 128;
    int n0 = ntile * 128;
    int t = threadIdx.x, lane = t & 63, wvv = t >> 6;
    int wr = wvv >> 1, wc = wvv & 1;

    __shared__ __attribute__((aligned(16))) char ldsb[33792];
    short* lds = (short*)ldsb;
    const unsigned short* abase = as_ + (size_t)b * CB_;
    const unsigned short* wbase = wsp + (size_t)3 * 384 * KS2;

    f32x4 acc[4][4] = {};
    for (int kk = 0; kk < 384; kk += 64) {     // hi pass only
        #pragma unroll
        for (int j = 0; j < 4; ++j) {
            int row = wvv * 32 + j * 8 + (lane >> 3);
            int g = (lane & 7) ^ (row & 7);
            async16(abase + (size_t)(n0 + row) * C_ + kk + g * 8, lds + (wvv * 32 + j * 8) * 64);
        }
        #pragma unroll
        for (int j = 0; j < 4; ++j) {
            int row = wvv * 32 + j * 8 + (lane >> 3);
            int g = (lane & 7) ^ (row & 7);
            async16(wbase + (size_t)(orow0 + row) * KS2 + 384 + kk + g * 8, lds + 8192 + (wvv * 32 + j * 8) * 64);
        }
        __syncthreads();
        #pragma unroll
        for (int ksb = 0; ksb < 2; ++ksb) {
            half8 af[4], bfr[4];
            #pragma unroll
            for (int mi = 0; mi < 4; ++mi) {
                int row = wr * 64 + mi * 16 + (lane & 15);
                int s = (ksb * 4 + (lane >> 4)) ^ (row & 7);
                af[mi] = *(const half8*)&lds[row * 64 + s * 8];
            }
            #pragma unroll
            for (int ni = 0; ni < 4; ++ni) {
                int row = wc * 64 + ni * 16 + (lane & 15);
                int s = (ksb * 4 + (lane >> 4)) ^ (row & 7);
                bfr[ni] = *(const half8*)&lds[8192 + row * 64 + s * 8];
            }
            #pragma unroll
            for (int mi = 0; mi < 4; ++mi)
                #pragma unroll
                for (int ni = 0; ni < 4; ++ni)
                    acc[mi][ni] = __builtin_amdgcn_mfma_f32_16x16x32_f16(af[mi], bfr[ni], acc[mi][ni], 0, 0, 0);
        }
        __syncthreads();
    }

    float s_bn[4], t_bn[4];
    #pragma unroll
    for (int ni = 0; ni < 4; ++ni) {
        int o = orow0 + wc * 64 + ni * 16 + (lane & 15);
        float g = pp.g[o], be = pp.be[o], mu = pp.mu[o], va = pp.va[o];
        float s = g / sqrtf(va + 1e-5f);
        s_bn[ni] = s; t_bn[ni] = be - mu * s;
    }
    float* fsm = (float*)ldsb;
    for (int half = 0; half < 2; ++half) {
        __syncthreads();
        if (wc == half) {
            #pragma unroll
            for (int mi = 0; mi < 4; ++mi)
                #pragma unroll
                for (int ni = 0; ni < 4; ++ni) {
                    int ol = ni * 16 + (lane & 15);
                    int nl = wr * 64 + mi * 16 + (lane >> 4) * 4;
                    f32x4 vv;
                    #pragma unroll
                    for (int r = 0; r < 4; ++r)
                        vv[r] = acc[mi][ni][r] * s_bn[ni] + t_bn[ni];
                    *(f32x4*)&fsm[ol * 132 + nl] = vv;
                }
        }
        __syncthreads();
        #pragma unroll
        for (int i = 0; i < 8; ++i) {
            int f = i * 256 + t;
            int o = f >> 5, slot = f & 31;
            f32x4 vv = *(const f32x4*)&fsm[o * 132 + slot * 4];
            *(f32x4*)(out + ((size_t)b * C_ + orow0 + half * 64 + o) * N_ + n0 + slot * 4) = vv;
        }
    }
}

extern "C" void kernel_launch(void* const* d_in, const int* in_sizes, int n_in,
                              void* d_out, int out_size, void* d_ws, size_t ws_size,
                              hipStream_t stream) {
    P5 pq { (const float*)d_in[1],  (const float*)d_in[2],  (const float*)d_in[3],
            (const float*)d_in[4],  (const float*)d_in[5] };
    P5 pk { (const float*)d_in[6],  (const float*)d_in[7],  (const float*)d_in[8],
            (const float*)d_in[9],  (const float*)d_in[10] };
    P5 pv { (const float*)d_in[11], (const float*)d_in[12], (const float*)d_in[13],
            (const float*)d_in[14], (const float*)d_in[15] };
    P5 pp { (const float*)d_in[16], (const float*)d_in[17], (const float*)d_in[18],
            (const float*)d_in[19], (const float*)d_in[20] };
    W4 w4 { pq.w, pk.w, pv.w, pp.w };

    char* ws = (char*)d_ws;
    const size_t S = (size_t)B_ * C_ * N_ * 2;
    unsigned short* xst = (unsigned short*)ws;
    unsigned short* qs  = (unsigned short*)(ws + S);
    unsigned short* ks  = (unsigned short*)(ws + 2 * S + 256);
    unsigned short* vs  = (unsigned short*)(ws + 3 * S + 512);
    float*          kvp = (float*)(ws + 4 * S + 768);                        // 2359296 B
    unsigned short* hig = (unsigned short*)(ws + 4 * S + 768 + 2359296);     // 393216 B
    unsigned short* log = (unsigned short*)(ws + 4 * S + 768 + 2359296 + 393216);
    unsigned short* wsp = (unsigned short*)(ws + 4 * S + 768 + 2359296 + 2 * 393216); // 2359296 B
    unsigned short* as_ = xst;

    kprep0<<<1344, 256, 0, stream>>>((const float*)d_in[0], xst, w4, wsp);
    k1_qkv<<<2304, 256, 0, stream>>>(xst, wsp, pq, pk, pv, qs, ks, vs);
    k2_kv<<<256, 256, 0, stream>>>(ks, vs, kvp);
    k2b_split<<<768, 256, 0, stream>>>(kvp, hig, log);
    k3_attn<<<1024, 256, 0, stream>>>(qs, hig, log, as_);
    k4_pconv<<<768, 256, 0, stream>>>(as_, hig /*unused shim*/ == hig ? wsp : wsp, pp, (float*)d_out);
}